// Round 2
// baseline (1459.988 us; speedup 1.0000x reference)
//
#include <hip/hip_runtime.h>

#define NN 268
#define NE 8192

// ---------------------------------------------------------------------------
// K1: per-graph edge prep. deg by src (self-loops zeroed), dinv,
// nw[e] = -dinv[src]*w*dinv[dst]. No CSR needed (cheb is edge-parallel).
// ---------------------------------------------------------------------------
__global__ __launch_bounds__(256) void k_edge_prep(
    const int* __restrict__ ei1, const float* __restrict__ ea1,
    const int* __restrict__ ei2, const float* __restrict__ ea2,
    float* __restrict__ nwall) {
  int g = blockIdx.x;
  const int* ei = (g < 64) ? (ei1 + (size_t)g * 2 * NE) : (ei2 + (size_t)(g - 64) * 2 * NE);
  const float* ea = (g < 64) ? (ea1 + (size_t)g * NE) : (ea2 + (size_t)(g - 64) * NE);
  __shared__ float deg[NN];
  __shared__ float dinv[NN];
  int t = threadIdx.x;
  for (int n = t; n < NN; n += 256) deg[n] = 0.f;
  __syncthreads();
  for (int e = t; e < NE; e += 256) {
    int s = ei[e], d = ei[NE + e];
    float w = (s == d) ? 0.f : ea[e];
    atomicAdd(&deg[s], w);
  }
  __syncthreads();
  for (int n = t; n < NN; n += 256) {
    float dv = deg[n];
    dinv[n] = dv > 0.f ? rsqrtf(dv) : 0.f;
  }
  __syncthreads();
  float* nwg = nwall + (size_t)g * NE;
  for (int e = t; e < NE; e += 256) {
    int s = ei[e], d = ei[NE + e];
    float w = (s == d) ? 0.f : ea[e];
    nwg[e] = -dinv[s] * w * dinv[d];
  }
}

// ---------------------------------------------------------------------------
// K2/K4: batched GEMM  Y[g] = A[g] @ [W[0]|W[1]|W[2]]  (per-graph A, shared W)
// A[g]: [268 x KD] row-major. W: [3][KD][SN]. Y: [g][268][NC], NC = 3*SN.
// Tile: 64 rows x NC cols per block, 256 threads, 4 x TNT micro-tile.
// ---------------------------------------------------------------------------
template <int KD, int NC, int SN, int TNT>
__global__ __launch_bounds__(256) void k_gemm_cat(
    const float* __restrict__ A1, const float* __restrict__ A2,
    const float* __restrict__ W, float* __restrict__ Y) {
  int g = blockIdx.y;
  int m0 = blockIdx.x * 64;
  const float* A = (g < 64) ? (A1 + (size_t)g * NN * KD) : (A2 + (size_t)(g - 64) * NN * KD);
  float* Yg = Y + (size_t)g * NN * NC;
  __shared__ float As[64][17];
  __shared__ float Bs[16][NC];
  int t = threadIdx.x;
  int tx = t & 15, ty = t >> 4;
  float acc[4][TNT];
#pragma unroll
  for (int i = 0; i < 4; ++i)
#pragma unroll
    for (int j = 0; j < TNT; ++j) acc[i][j] = 0.f;

  for (int k0 = 0; k0 < KD; k0 += 16) {
    int klim = KD - k0; if (klim > 16) klim = 16;
    {
      int kk = t & 15, rb = t >> 4;
#pragma unroll
      for (int i = 0; i < 4; ++i) {
        int r = rb + i * 16;
        int row = m0 + r;
        As[r][kk] = (row < NN && kk < klim) ? A[(size_t)row * KD + k0 + kk] : 0.f;
      }
    }
    for (int i = t; i < 16 * NC; i += 256) {
      int kk = i / NC, c = i - kk * NC;
      int kb = c / SN, j = c - kb * SN;
      Bs[kk][c] = (kk < klim) ? W[((size_t)kb * KD + (k0 + kk)) * SN + j] : 0.f;
    }
    __syncthreads();
#pragma unroll
    for (int kk = 0; kk < 16; ++kk) {
      float a[4];
#pragma unroll
      for (int i = 0; i < 4; ++i) a[i] = As[ty * 4 + i][kk];
#pragma unroll
      for (int j = 0; j < TNT; ++j) {
        float b = Bs[kk][tx * TNT + j];
#pragma unroll
        for (int i = 0; i < 4; ++i) acc[i][j] += a[i] * b;
      }
    }
    __syncthreads();
  }
#pragma unroll
  for (int i = 0; i < 4; ++i) {
    int row = m0 + ty * 4 + i;
    if (row < NN) {
#pragma unroll
      for (int j = 0; j < TNT; ++j) Yg[(size_t)row * NC + tx * TNT + j] = acc[i][j];
    }
  }
}

// ---------------------------------------------------------------------------
// Edge-parallel scatter: T[d][f] += nw_e * S[s][f] for all edges, 16 feats.
// 16 lanes/group share one edge (f = t&15) -> edge loads broadcast, LDS
// addresses d*16+f hit 16 consecutive banks. Trip count is compile-time
// (NE/16 = 512) -> unrollable, independent iterations pipeline freely.
// ---------------------------------------------------------------------------
__device__ __forceinline__ void scatter16(
    float* __restrict__ T, const float* __restrict__ S,
    const int* __restrict__ esrc, const int* __restrict__ edst,
    const float* __restrict__ enw, int t) {
  int f = t & 15, grp = t >> 4;
#pragma unroll 4
  for (int e = grp; e < NE; e += 16) {
    int s = esrc[e], d = edst[e];
    float v = enw[e] * S[s * 16 + f];
    atomicAdd(&T[d * 16 + f], v);
  }
}

// ---------------------------------------------------------------------------
// K3: cheb1 combine. H1 = relu(Y0 - Y2 + L*(Y1 + 2*L*Y2) + b1)
// Y cols: [0:64)=Y0, [64:128)=Y1, [128:192)=Y2. Block = (graph, 16-feat chunk).
// ---------------------------------------------------------------------------
__global__ __launch_bounds__(256) void k_cheb1(
    const float* __restrict__ Y, const int* __restrict__ ei1,
    const int* __restrict__ ei2, const float* __restrict__ nwall,
    const float* __restrict__ b1, float* __restrict__ H1) {
  int g = blockIdx.y, fb = blockIdx.x * 16;
  const float* Yg = Y + (size_t)g * NN * 192;
  const int* ei = (g < 64) ? (ei1 + (size_t)g * 2 * NE) : (ei2 + (size_t)(g - 64) * 2 * NE);
  const int* esrc = ei;
  const int* edst = ei + NE;
  const float* enw = nwall + (size_t)g * NE;
  __shared__ float S[NN * 16];
  __shared__ float T[NN * 16];
  int t = threadIdx.x;
  for (int i = t; i < NN * 16; i += 256) {
    int n = i >> 4, f = i & 15;
    S[i] = Yg[n * 192 + 128 + fb + f];  // Y2 chunk
    T[i] = 0.f;
  }
  __syncthreads();
  scatter16(T, S, esrc, edst, enw, t);  // T = L*Y2
  __syncthreads();
  for (int i = t; i < NN * 16; i += 256) {
    int n = i >> 4, f = i & 15;
    S[i] = Yg[n * 192 + 64 + fb + f] + 2.f * T[i];  // U = Y1 + 2*L*Y2
  }
  __syncthreads();
  for (int i = t; i < NN * 16; i += 256) T[i] = 0.f;
  __syncthreads();
  scatter16(T, S, esrc, edst, enw, t);  // T = L*U = L*Y1 + 2*L*L*Y2
  __syncthreads();
  for (int i = t; i < NN * 16; i += 256) {
    int n = i >> 4, f = i & 15;
    int c = fb + f;
    float v = Yg[n * 192 + c] - Yg[n * 192 + 128 + c] + T[i] + b1[c];
    H1[((size_t)g * NN + n) * 64 + c] = fmaxf(v, 0.f);
  }
}

// ---------------------------------------------------------------------------
// K5: cheb2 combine, F=32, Yb cols [0:32|32:64|64:96].
// Output written TRANSPOSED: H2T[g][f][n] (rows of classifier GEMM).
// ---------------------------------------------------------------------------
__global__ __launch_bounds__(256) void k_cheb2(
    const float* __restrict__ Yb, const int* __restrict__ ei1,
    const int* __restrict__ ei2, const float* __restrict__ nwall,
    const float* __restrict__ b4, float* __restrict__ H2T) {
  int g = blockIdx.y, fb = blockIdx.x * 16;
  const float* Yg = Yb + (size_t)g * NN * 96;
  const int* ei = (g < 64) ? (ei1 + (size_t)g * 2 * NE) : (ei2 + (size_t)(g - 64) * 2 * NE);
  const int* esrc = ei;
  const int* edst = ei + NE;
  const float* enw = nwall + (size_t)g * NE;
  __shared__ float S[NN * 16];
  __shared__ float T[NN * 16];
  int t = threadIdx.x;
  for (int i = t; i < NN * 16; i += 256) {
    int n = i >> 4, f = i & 15;
    S[i] = Yg[n * 96 + 64 + fb + f];  // Y2' chunk
    T[i] = 0.f;
  }
  __syncthreads();
  scatter16(T, S, esrc, edst, enw, t);
  __syncthreads();
  for (int i = t; i < NN * 16; i += 256) {
    int n = i >> 4, f = i & 15;
    S[i] = Yg[n * 96 + 32 + fb + f] + 2.f * T[i];
  }
  __syncthreads();
  for (int i = t; i < NN * 16; i += 256) T[i] = 0.f;
  __syncthreads();
  scatter16(T, S, esrc, edst, enw, t);
  __syncthreads();
  for (int i = t; i < NN * 16; i += 256) {
    int n = i >> 4, f = i & 15;
    int c = fb + f;
    float v = Yg[n * 96 + c] - Yg[n * 96 + 64 + c] + T[i] + b4[c];
    H2T[(size_t)g * 32 * NN + (size_t)c * NN + n] = fmaxf(v, 0.f);
  }
}

// ---------------------------------------------------------------------------
// K6/K7: plain GEMM + bias (+relu). A:[M x KD], W:[KD x NC], out:[M x NC].
// ---------------------------------------------------------------------------
template <int KD, int NC, int NCP, int TNT, bool RELU>
__global__ __launch_bounds__(256) void k_gemm_bias(
    const float* __restrict__ A, const float* __restrict__ W,
    const float* __restrict__ bias, float* __restrict__ out, int M) {
  int m0 = blockIdx.x * 64;
  __shared__ float As[64][17];
  __shared__ float Bs[16][NCP];
  int t = threadIdx.x;
  int tx = t & 15, ty = t >> 4;
  float acc[4][TNT];
#pragma unroll
  for (int i = 0; i < 4; ++i)
#pragma unroll
    for (int j = 0; j < TNT; ++j) acc[i][j] = 0.f;

  for (int k0 = 0; k0 < KD; k0 += 16) {
    int klim = KD - k0; if (klim > 16) klim = 16;
    {
      int kk = t & 15, rb = t >> 4;
#pragma unroll
      for (int i = 0; i < 4; ++i) {
        int r = rb + i * 16;
        int row = m0 + r;
        As[r][kk] = (row < M && kk < klim) ? A[(size_t)row * KD + k0 + kk] : 0.f;
      }
    }
    for (int i = t; i < 16 * NCP; i += 256) {
      int kk = i / NCP, c = i - kk * NCP;
      Bs[kk][c] = (kk < klim && c < NC) ? W[(size_t)(k0 + kk) * NC + c] : 0.f;
    }
    __syncthreads();
#pragma unroll
    for (int kk = 0; kk < 16; ++kk) {
      float a[4];
#pragma unroll
      for (int i = 0; i < 4; ++i) a[i] = As[ty * 4 + i][kk];
#pragma unroll
      for (int j = 0; j < TNT; ++j) {
        float b = Bs[kk][tx * TNT + j];
#pragma unroll
        for (int i = 0; i < 4; ++i) acc[i][j] += a[i] * b;
      }
    }
    __syncthreads();
  }
#pragma unroll
  for (int i = 0; i < 4; ++i) {
    int row = m0 + ty * 4 + i;
    if (row < M) {
#pragma unroll
      for (int j = 0; j < TNT; ++j) {
        int c = tx * TNT + j;
        if (c < NC) {
          float v = acc[i][j] + bias[c];
          if (RELU) v = fmaxf(v, 0.f);
          out[(size_t)row * NC + c] = v;
        }
      }
    }
  }
}

// ---------------------------------------------------------------------------
// K8: out[r] = Z2[r][:] . Wc3 + bc3  (r = g*32 + c, matches d_out layout)
// ---------------------------------------------------------------------------
__global__ __launch_bounds__(256) void k_final(
    const float* __restrict__ Z2, const float* __restrict__ Wc3,
    const float* __restrict__ bc3, float* __restrict__ out) {
  __shared__ float Zs[256 * 61];
  __shared__ float w3[60];
  int b = blockIdx.x, t = threadIdx.x;
  const float* src = Z2 + (size_t)b * 256 * 60;
  for (int i = t; i < 256 * 60; i += 256) {
    int row = i / 60, col = i - row * 60;
    Zs[row * 61 + col] = src[i];
  }
  if (t < 60) w3[t] = Wc3[t];
  __syncthreads();
  float acc = bc3[0];
#pragma unroll
  for (int k = 0; k < 60; ++k) acc += Zs[t * 61 + k] * w3[k];
  out[(size_t)b * 256 + t] = acc;
}

// ---------------------------------------------------------------------------
// Workspace layout (bytes):
//   0         nw    f32 [128][8192]          4,194,304
//   4194304   Y     f32 [128][268][192]     26,345,472  (reused as Y2b [..][96] by K4/K5)
//   30539776  H1    f32 [128][268][64]       8,781,824  (reused as H2T [128][32][268] by K5+)
//   39321600  Z1    f32 [128][32][100]       1,638,400
//   40960000  Z2    f32 [128][32][60]          983,040
// total ~41.9 MB
// ---------------------------------------------------------------------------
extern "C" void kernel_launch(void* const* d_in, const int* in_sizes, int n_in,
                              void* d_out, int out_size, void* d_ws, size_t ws_size,
                              hipStream_t stream) {
  (void)in_sizes; (void)n_in; (void)out_size; (void)ws_size;
  const float* x1  = (const float*)d_in[0];
  const int*   ei1 = (const int*)d_in[1];
  const float* ea1 = (const float*)d_in[2];
  const float* x2  = (const float*)d_in[3];
  const int*   ei2 = (const int*)d_in[4];
  const float* ea2 = (const float*)d_in[5];
  const float* W1  = (const float*)d_in[6];
  const float* b1  = (const float*)d_in[7];
  const float* W4  = (const float*)d_in[8];
  const float* b4  = (const float*)d_in[9];
  const float* Wc1 = (const float*)d_in[10];
  const float* bc1 = (const float*)d_in[11];
  const float* Wc2 = (const float*)d_in[12];
  const float* bc2 = (const float*)d_in[13];
  const float* Wc3 = (const float*)d_in[14];
  const float* bc3 = (const float*)d_in[15];

  char* ws = (char*)d_ws;
  float* nw  = (float*)(ws + 0);
  float* Y   = (float*)(ws + 4194304);
  float* H1  = (float*)(ws + 30539776);
  float* H2T = (float*)(ws + 30539776);
  float* Z1  = (float*)(ws + 39321600);
  float* Z2  = (float*)(ws + 40960000);
  float* out = (float*)d_out;

  k_edge_prep<<<128, 256, 0, stream>>>(ei1, ea1, ei2, ea2, nw);
  // Y = X @ [W1_0|W1_1|W1_2]   (M=268/graph, K=268, N=192)
  k_gemm_cat<268, 192, 64, 12><<<dim3(5, 128), 256, 0, stream>>>(x1, x2, W1, Y);
  // H1 = relu(Y0 - Y2 + L*(Y1 + 2*L*Y2) + b1)
  k_cheb1<<<dim3(4, 128), 256, 0, stream>>>(Y, ei1, ei2, nw, b1, H1);
  // Y2b = H1 @ [W4_0|W4_1|W4_2]  (K=64, N=96), written over the Y region
  k_gemm_cat<64, 96, 32, 6><<<dim3(5, 128), 256, 0, stream>>>(
      H1, H1 + (size_t)64 * NN * 64, W4, Y);
  // H2T = relu(cheb2) transposed -> [g][32][268], written over H1 region
  k_cheb2<<<dim3(2, 128), 256, 0, stream>>>(Y, ei1, ei2, nw, b4, H2T);
  // classifier: stacked rows M = 128*32 = 4096 share weights
  k_gemm_bias<268, 100, 112, 7, true><<<64, 256, 0, stream>>>(H2T, Wc1, bc1, Z1, 4096);
  k_gemm_bias<100, 60, 64, 4, true><<<64, 256, 0, stream>>>(Z1, Wc2, bc2, Z2, 4096);
  k_final<<<16, 256, 0, stream>>>(Z2, Wc3, bc3, out);
}

// Round 3
// 554.899 us; speedup vs baseline: 2.6311x; 2.6311x over previous
//
#include <hip/hip_runtime.h>

#define NN 268
#define NE 8192

// ---------------------------------------------------------------------------
// K1: per-graph edge prep. deg by src, dinv, nw = -dinv[src]*w*dinv[dst]
// (self-loops zeroed), CSR sorted by dst -> (src, nw) pairs + row_ptr.
// ---------------------------------------------------------------------------
__global__ __launch_bounds__(256) void k_edge_prep(
    const int* __restrict__ ei1, const float* __restrict__ ea1,
    const int* __restrict__ ei2, const float* __restrict__ ea2,
    int2* __restrict__ csr, int* __restrict__ rowptr) {
  int g = blockIdx.x;
  const int* ei = (g < 64) ? (ei1 + (size_t)g * 2 * NE) : (ei2 + (size_t)(g - 64) * 2 * NE);
  const float* ea = (g < 64) ? (ea1 + (size_t)g * NE) : (ea2 + (size_t)(g - 64) * NE);
  __shared__ float deg[NN];
  __shared__ float dinv[NN];
  __shared__ int cnt[NN];
  __shared__ int rp[NN + 1];
  int t = threadIdx.x;
  for (int n = t; n < NN; n += 256) { deg[n] = 0.f; cnt[n] = 0; }
  __syncthreads();
  for (int e = t; e < NE; e += 256) {
    int s = ei[e], d = ei[NE + e];
    float w = ea[e];
    if (s == d) w = 0.f;
    atomicAdd(&deg[s], w);
    atomicAdd(&cnt[d], 1);
  }
  __syncthreads();
  for (int n = t; n < NN; n += 256) {
    float dv = deg[n];
    dinv[n] = dv > 0.f ? rsqrtf(dv) : 0.f;
  }
  __syncthreads();
  if (t == 0) {
    int acc = 0;
    for (int n = 0; n < NN; ++n) { rp[n] = acc; acc += cnt[n]; }
    rp[NN] = acc;
  }
  __syncthreads();
  for (int n = t; n <= NN; n += 256) rowptr[g * 272 + n] = rp[n];
  for (int n = t; n < NN; n += 256) cnt[n] = rp[n];
  __syncthreads();
  for (int e = t; e < NE; e += 256) {
    int s = ei[e], d = ei[NE + e];
    float w = ea[e];
    if (s == d) w = 0.f;
    float nw = -dinv[s] * w * dinv[d];
    int pos = atomicAdd(&cnt[d], 1);
    csr[(size_t)g * NE + pos] = make_int2(s, __float_as_int(nw));
  }
}

// ---------------------------------------------------------------------------
// K2/K4: batched GEMM  Y[g] = A[g] @ [W[0]|W[1]|W[2]]  (per-graph A, shared W)
// A[g]: [268 x KD] row-major. W: [3][KD][SN]. Y: [g][268][NC], NC = 3*SN.
// Tile: 64 rows x NC cols per block, 256 threads, 4 x TNT micro-tile.
// ---------------------------------------------------------------------------
template <int KD, int NC, int SN, int TNT>
__global__ __launch_bounds__(256) void k_gemm_cat(
    const float* __restrict__ A1, const float* __restrict__ A2,
    const float* __restrict__ W, float* __restrict__ Y) {
  int g = blockIdx.y;
  int m0 = blockIdx.x * 64;
  const float* A = (g < 64) ? (A1 + (size_t)g * NN * KD) : (A2 + (size_t)(g - 64) * NN * KD);
  float* Yg = Y + (size_t)g * NN * NC;
  __shared__ float As[64][17];
  __shared__ float Bs[16][NC];
  int t = threadIdx.x;
  int tx = t & 15, ty = t >> 4;
  float acc[4][TNT];
#pragma unroll
  for (int i = 0; i < 4; ++i)
#pragma unroll
    for (int j = 0; j < TNT; ++j) acc[i][j] = 0.f;

  for (int k0 = 0; k0 < KD; k0 += 16) {
    int klim = KD - k0; if (klim > 16) klim = 16;
    {
      int kk = t & 15, rb = t >> 4;
#pragma unroll
      for (int i = 0; i < 4; ++i) {
        int r = rb + i * 16;
        int row = m0 + r;
        As[r][kk] = (row < NN && kk < klim) ? A[(size_t)row * KD + k0 + kk] : 0.f;
      }
    }
    for (int i = t; i < 16 * NC; i += 256) {
      int kk = i / NC, c = i - kk * NC;
      int kb = c / SN, j = c - kb * SN;
      Bs[kk][c] = (kk < klim) ? W[((size_t)kb * KD + (k0 + kk)) * SN + j] : 0.f;
    }
    __syncthreads();
#pragma unroll
    for (int kk = 0; kk < 16; ++kk) {
      float a[4];
#pragma unroll
      for (int i = 0; i < 4; ++i) a[i] = As[ty * 4 + i][kk];
#pragma unroll
      for (int j = 0; j < TNT; ++j) {
        float b = Bs[kk][tx * TNT + j];
#pragma unroll
        for (int i = 0; i < 4; ++i) acc[i][j] += a[i] * b;
      }
    }
    __syncthreads();
  }
#pragma unroll
  for (int i = 0; i < 4; ++i) {
    int row = m0 + ty * 4 + i;
    if (row < NN) {
#pragma unroll
      for (int j = 0; j < TNT; ++j) Yg[(size_t)row * NC + tx * TNT + j] = acc[i][j];
    }
  }
}

// ---------------------------------------------------------------------------
// CSR gather over an 8-feature chunk:
// dst[n][0:8] = sum_{e: dst_e = n} nw_e * src[src_e][0:8]
// item = (node, float4-group); adjacent lanes share a node's edge list so the
// int2 CSR loads broadcast. One writer per output -> no atomics.
// ---------------------------------------------------------------------------
__device__ __forceinline__ void gather8(float* __restrict__ dst, const float* __restrict__ src,
                                        const int2* __restrict__ cs, const int* __restrict__ rp,
                                        int t) {
  for (int item = t; item < NN * 2; item += 256) {
    int n = item >> 1, fg = item & 1;
    float4 r = make_float4(0.f, 0.f, 0.f, 0.f);
    int e1 = rp[n + 1];
    for (int e = rp[n]; e < e1; ++e) {
      int2 p = cs[e];
      float nw = __int_as_float(p.y);
      float4 sv = *(const float4*)(src + p.x * 8 + fg * 4);
      r.x += nw * sv.x; r.y += nw * sv.y; r.z += nw * sv.z; r.w += nw * sv.w;
    }
    *(float4*)(dst + n * 8 + fg * 4) = r;
  }
}

// ---------------------------------------------------------------------------
// K3: cheb1 combine. H1 = relu(Y0 - Y2 + L*(Y1 + 2*L*Y2) + b1)
// Y cols: [0:64)=Y0, [64:128)=Y1, [128:192)=Y2. Block = (graph, 8-feat chunk).
// ---------------------------------------------------------------------------
__global__ __launch_bounds__(256) void k_cheb1(
    const float* __restrict__ Y, const int2* __restrict__ csr, const int* __restrict__ rowptr,
    const float* __restrict__ b1, float* __restrict__ H1) {
  int g = blockIdx.y, fb = blockIdx.x * 8;
  const float* Yg = Y + (size_t)g * NN * 192;
  const int2* cs = csr + (size_t)g * NE;
  __shared__ __align__(16) float S[NN * 8];
  __shared__ __align__(16) float T[NN * 8];
  __shared__ int rp[NN + 1];
  int t = threadIdx.x;
  for (int i = t; i < NN + 1; i += 256) rp[i] = rowptr[g * 272 + i];
  for (int i = t; i < NN * 8; i += 256) {
    int n = i >> 3, f = i & 7;
    S[i] = Yg[n * 192 + 128 + fb + f];  // Y2 chunk
  }
  __syncthreads();
  gather8(T, S, cs, rp, t);  // T = L*Y2
  __syncthreads();
  for (int i = t; i < NN * 8; i += 256) {
    int n = i >> 3, f = i & 7;
    S[i] = Yg[n * 192 + 64 + fb + f] + 2.f * T[i];  // U = Y1 + 2*L*Y2
  }
  __syncthreads();
  gather8(T, S, cs, rp, t);  // T = L*U = L*Y1 + 2*L*L*Y2
  __syncthreads();
  for (int i = t; i < NN * 8; i += 256) {
    int n = i >> 3, f = i & 7;
    int c = fb + f;
    float v = Yg[n * 192 + c] - Yg[n * 192 + 128 + c] + T[i] + b1[c];
    H1[((size_t)g * NN + n) * 64 + c] = fmaxf(v, 0.f);
  }
}

// ---------------------------------------------------------------------------
// K5: cheb2 combine, 8-feat chunks, Yb cols [0:32|32:64|64:96].
// Output written TRANSPOSED: H2T[g][f][n] (rows of classifier GEMM).
// ---------------------------------------------------------------------------
__global__ __launch_bounds__(256) void k_cheb2(
    const float* __restrict__ Yb, const int2* __restrict__ csr, const int* __restrict__ rowptr,
    const float* __restrict__ b4, float* __restrict__ H2T) {
  int g = blockIdx.y, fb = blockIdx.x * 8;
  const float* Yg = Yb + (size_t)g * NN * 96;
  const int2* cs = csr + (size_t)g * NE;
  __shared__ __align__(16) float S[NN * 8];
  __shared__ __align__(16) float T[NN * 8];
  __shared__ int rp[NN + 1];
  int t = threadIdx.x;
  for (int i = t; i < NN + 1; i += 256) rp[i] = rowptr[g * 272 + i];
  for (int i = t; i < NN * 8; i += 256) {
    int n = i >> 3, f = i & 7;
    S[i] = Yg[n * 96 + 64 + fb + f];  // Y2' chunk
  }
  __syncthreads();
  gather8(T, S, cs, rp, t);  // T = L*Y2'
  __syncthreads();
  for (int i = t; i < NN * 8; i += 256) {
    int n = i >> 3, f = i & 7;
    S[i] = Yg[n * 96 + 32 + fb + f] + 2.f * T[i];  // U
  }
  __syncthreads();
  gather8(T, S, cs, rp, t);  // T = L*U
  __syncthreads();
  for (int i = t; i < NN * 8; i += 256) {
    int n = i >> 3, f = i & 7;
    int c = fb + f;
    float v = Yg[n * 96 + c] - Yg[n * 96 + 64 + c] + T[i] + b4[c];
    H2T[(size_t)g * 32 * NN + (size_t)c * NN + n] = fmaxf(v, 0.f);
  }
}

// ---------------------------------------------------------------------------
// K6/K7: plain GEMM + bias (+relu). A:[M x KD], W:[KD x NC], out:[M x NC].
// ---------------------------------------------------------------------------
template <int KD, int NC, int NCP, int TNT, bool RELU>
__global__ __launch_bounds__(256) void k_gemm_bias(
    const float* __restrict__ A, const float* __restrict__ W,
    const float* __restrict__ bias, float* __restrict__ out, int M) {
  int m0 = blockIdx.x * 64;
  __shared__ float As[64][17];
  __shared__ float Bs[16][NCP];
  int t = threadIdx.x;
  int tx = t & 15, ty = t >> 4;
  float acc[4][TNT];
#pragma unroll
  for (int i = 0; i < 4; ++i)
#pragma unroll
    for (int j = 0; j < TNT; ++j) acc[i][j] = 0.f;

  for (int k0 = 0; k0 < KD; k0 += 16) {
    int klim = KD - k0; if (klim > 16) klim = 16;
    {
      int kk = t & 15, rb = t >> 4;
#pragma unroll
      for (int i = 0; i < 4; ++i) {
        int r = rb + i * 16;
        int row = m0 + r;
        As[r][kk] = (row < M && kk < klim) ? A[(size_t)row * KD + k0 + kk] : 0.f;
      }
    }
    for (int i = t; i < 16 * NCP; i += 256) {
      int kk = i / NCP, c = i - kk * NCP;
      Bs[kk][c] = (kk < klim && c < NC) ? W[(size_t)(k0 + kk) * NC + c] : 0.f;
    }
    __syncthreads();
#pragma unroll
    for (int kk = 0; kk < 16; ++kk) {
      float a[4];
#pragma unroll
      for (int i = 0; i < 4; ++i) a[i] = As[ty * 4 + i][kk];
#pragma unroll
      for (int j = 0; j < TNT; ++j) {
        float b = Bs[kk][tx * TNT + j];
#pragma unroll
        for (int i = 0; i < 4; ++i) acc[i][j] += a[i] * b;
      }
    }
    __syncthreads();
  }
#pragma unroll
  for (int i = 0; i < 4; ++i) {
    int row = m0 + ty * 4 + i;
    if (row < M) {
#pragma unroll
      for (int j = 0; j < TNT; ++j) {
        int c = tx * TNT + j;
        if (c < NC) {
          float v = acc[i][j] + bias[c];
          if (RELU) v = fmaxf(v, 0.f);
          out[(size_t)row * NC + c] = v;
        }
      }
    }
  }
}

// ---------------------------------------------------------------------------
// K8: out[r] = Z2[r][:] . Wc3 + bc3  (r = g*32 + c, matches d_out layout)
// ---------------------------------------------------------------------------
__global__ __launch_bounds__(256) void k_final(
    const float* __restrict__ Z2, const float* __restrict__ Wc3,
    const float* __restrict__ bc3, float* __restrict__ out) {
  __shared__ float Zs[256 * 61];
  __shared__ float w3[60];
  int b = blockIdx.x, t = threadIdx.x;
  const float* src = Z2 + (size_t)b * 256 * 60;
  for (int i = t; i < 256 * 60; i += 256) {
    int row = i / 60, col = i - row * 60;
    Zs[row * 61 + col] = src[i];
  }
  if (t < 60) w3[t] = Wc3[t];
  __syncthreads();
  float acc = bc3[0];
#pragma unroll
  for (int k = 0; k < 60; ++k) acc += Zs[t * 61 + k] * w3[k];
  out[(size_t)b * 256 + t] = acc;
}

// ---------------------------------------------------------------------------
// Workspace layout (bytes) — identical to the proven round-0 layout:
//   0         csr   int2[128][8192]          8,388,608
//   8388608   rp    int [128][272]             139,264
//   8527872   Y     f32 [128][268][192]     26,345,472  (reused as Y2b [..][96] by K4/K5)
//   34873344  H1    f32 [128][268][64]       8,781,824  (H2T [128][32][268] overwrites
//                                                        its first 4.39MB after H1 is dead)
//   39264256  Z1    f32 [128][32][100]       1,638,400  (overlaps dead H1 tail — safe:
//                                                        H1 last read by gemm_cat#2)
//   40902656  Z2    f32 [128][32][60]          983,040
// total ~41.9 MB
// ---------------------------------------------------------------------------
extern "C" void kernel_launch(void* const* d_in, const int* in_sizes, int n_in,
                              void* d_out, int out_size, void* d_ws, size_t ws_size,
                              hipStream_t stream) {
  (void)in_sizes; (void)n_in; (void)out_size; (void)ws_size;
  const float* x1  = (const float*)d_in[0];
  const int*   ei1 = (const int*)d_in[1];
  const float* ea1 = (const float*)d_in[2];
  const float* x2  = (const float*)d_in[3];
  const int*   ei2 = (const int*)d_in[4];
  const float* ea2 = (const float*)d_in[5];
  const float* W1  = (const float*)d_in[6];
  const float* b1  = (const float*)d_in[7];
  const float* W4  = (const float*)d_in[8];
  const float* b4  = (const float*)d_in[9];
  const float* Wc1 = (const float*)d_in[10];
  const float* bc1 = (const float*)d_in[11];
  const float* Wc2 = (const float*)d_in[12];
  const float* bc2 = (const float*)d_in[13];
  const float* Wc3 = (const float*)d_in[14];
  const float* bc3 = (const float*)d_in[15];

  char* ws = (char*)d_ws;
  int2*  csr = (int2*)(ws + 0);
  int*   rp  = (int*)(ws + 8388608);
  float* Y   = (float*)(ws + 8527872);
  float* H1  = (float*)(ws + 34873344);
  float* H2T = (float*)(ws + 34873344);
  float* Z1  = (float*)(ws + 39264256);
  float* Z2  = (float*)(ws + 40902656);
  float* out = (float*)d_out;

  k_edge_prep<<<128, 256, 0, stream>>>(ei1, ea1, ei2, ea2, csr, rp);
  // Y = X @ [W1_0|W1_1|W1_2]   (M=268/graph, K=268, N=192)
  k_gemm_cat<268, 192, 64, 12><<<dim3(5, 128), 256, 0, stream>>>(x1, x2, W1, Y);
  // H1 = relu(Y0 - Y2 + L*(Y1 + 2*L*Y2) + b1)
  k_cheb1<<<dim3(8, 128), 256, 0, stream>>>(Y, csr, rp, b1, H1);
  // Y2b = H1 @ [W4_0|W4_1|W4_2]  (K=64, N=96), written over the Y region
  k_gemm_cat<64, 96, 32, 6><<<dim3(5, 128), 256, 0, stream>>>(
      H1, H1 + (size_t)64 * NN * 64, W4, Y);
  // H2T = relu(cheb2) transposed -> [g][32][268], written over H1 region
  k_cheb2<<<dim3(4, 128), 256, 0, stream>>>(Y, csr, rp, b4, H2T);
  // classifier: stacked rows M = 128*32 = 4096 share weights
  k_gemm_bias<268, 100, 112, 7, true><<<64, 256, 0, stream>>>(H2T, Wc1, bc1, Z1, 4096);
  k_gemm_bias<100, 60, 64, 4, true><<<64, 256, 0, stream>>>(Z1, Wc2, bc2, Z2, 4096);
  k_final<<<16, 256, 0, stream>>>(Z2, Wc3, bc3, out);
}

// Round 4
// 461.509 us; speedup vs baseline: 3.1635x; 1.2024x over previous
//
#include <hip/hip_runtime.h>
#include <hip/hip_bf16.h>

#define NN 268
#define NE 8192
#define KP 288  // K=268 padded to multiple of 32

typedef short short8 __attribute__((ext_vector_type(8)));   // 8 bf16 = 4 VGPR
typedef float f32x4 __attribute__((ext_vector_type(4)));

// ---------------------------------------------------------------------------
// K1: per-graph edge prep. deg by src, dinv, nw = -dinv[src]*w*dinv[dst]
// (self-loops zeroed), CSR sorted by dst -> (src, nw) pairs + row_ptr.
// ---------------------------------------------------------------------------
__global__ __launch_bounds__(256) void k_edge_prep(
    const int* __restrict__ ei1, const float* __restrict__ ea1,
    const int* __restrict__ ei2, const float* __restrict__ ea2,
    int2* __restrict__ csr, int* __restrict__ rowptr) {
  int g = blockIdx.x;
  const int* ei = (g < 64) ? (ei1 + (size_t)g * 2 * NE) : (ei2 + (size_t)(g - 64) * 2 * NE);
  const float* ea = (g < 64) ? (ea1 + (size_t)g * NE) : (ea2 + (size_t)(g - 64) * NE);
  __shared__ float deg[NN];
  __shared__ float dinv[NN];
  __shared__ int cnt[NN];
  __shared__ int rp[NN + 1];
  int t = threadIdx.x;
  for (int n = t; n < NN; n += 256) { deg[n] = 0.f; cnt[n] = 0; }
  __syncthreads();
  for (int e = t; e < NE; e += 256) {
    int s = ei[e], d = ei[NE + e];
    float w = ea[e];
    if (s == d) w = 0.f;
    atomicAdd(&deg[s], w);
    atomicAdd(&cnt[d], 1);
  }
  __syncthreads();
  for (int n = t; n < NN; n += 256) {
    float dv = deg[n];
    dinv[n] = dv > 0.f ? rsqrtf(dv) : 0.f;
  }
  __syncthreads();
  if (t == 0) {
    int acc = 0;
    for (int n = 0; n < NN; ++n) { rp[n] = acc; acc += cnt[n]; }
    rp[NN] = acc;
  }
  __syncthreads();
  for (int n = t; n <= NN; n += 256) rowptr[g * 272 + n] = rp[n];
  for (int n = t; n < NN; n += 256) cnt[n] = rp[n];
  __syncthreads();
  for (int e = t; e < NE; e += 256) {
    int s = ei[e], d = ei[NE + e];
    float w = ea[e];
    if (s == d) w = 0.f;
    float nw = -dinv[s] * w * dinv[d];
    int pos = atomicAdd(&cnt[d], 1);
    csr[(size_t)g * NE + pos] = make_int2(s, __float_as_int(nw));
  }
}

// ---------------------------------------------------------------------------
// K1b: W1 [3][268][64] f32 -> WbT [192][288] bf16, WbT[n][k] = W1[n>>6][k][n&63]
// (zero-padded k>=268). Tiny (55K elems), runs once before the MFMA GEMM.
// ---------------------------------------------------------------------------
__global__ __launch_bounds__(256) void k_conv_w(
    const float* __restrict__ W1, short* __restrict__ WbT) {
  int idx = blockIdx.x * 256 + threadIdx.x;  // 192*288 = 55296
  if (idx >= 192 * KP) return;
  int n = idx / KP, kp = idx - n * KP;
  int kb = n >> 6, j = n & 63;
  float v = (kp < 268) ? W1[((size_t)kb * 268 + kp) * 64 + j] : 0.f;
  __hip_bfloat16 h = __float2bfloat16(v);
  WbT[idx] = *reinterpret_cast<short*>(&h);
}

__device__ __forceinline__ short f2bf(float f) {
  __hip_bfloat16 h = __float2bfloat16(f);
  return *reinterpret_cast<short*>(&h);
}

// ---------------------------------------------------------------------------
// K2: big GEMM on MFMA.  Y[g] = X[g] @ [W1_0|W1_1|W1_2]  (M=268,K=268,N=192)
// X staged fp32->bf16 inline (X read once, no converted copy in HBM).
// Block: 64 rows x 192 cols, 4 waves, each wave 2x6 16x16 tiles.
// K-chunk 32 (one MFMA K). LDS rows padded to 40 shorts (80B: 16B-aligned,
// <=2-way banks). Accumulate fp32, store f32 Y (cheb1 unchanged).
// ---------------------------------------------------------------------------
__global__ __launch_bounds__(256) void k_gemm1_mfma(
    const float* __restrict__ x1, const float* __restrict__ x2,
    const short* __restrict__ WbT, float* __restrict__ Y) {
  int g = blockIdx.y;
  int m0 = blockIdx.x * 64;
  const float* A32 = (g < 64) ? (x1 + (size_t)g * NN * 268) : (x2 + (size_t)(g - 64) * NN * 268);
  float* Yg = Y + (size_t)g * NN * 192;
  __shared__ __align__(16) short As[64][40];
  __shared__ __align__(16) short Bs[192][40];
  int t = threadIdx.x;
  int w = t >> 6, lane = t & 63;
  int quad = lane >> 4, l16 = lane & 15;
  int mh = w & 1, nh = w >> 1;
  f32x4 acc[2][6];
#pragma unroll
  for (int mi = 0; mi < 2; ++mi)
#pragma unroll
    for (int ni = 0; ni < 6; ++ni) acc[mi][ni] = (f32x4){0.f, 0.f, 0.f, 0.f};

  int sr = t >> 2, sko = (t & 3) * 8;  // staging row / k-offset (8 bf16 = 16B)
  for (int k0 = 0; k0 < KP; k0 += 32) {
    // stage A: 64 rows x 32 k, fp32 -> bf16
    {
      int row = m0 + sr;
      int k = k0 + sko;
      float4 va = make_float4(0.f, 0.f, 0.f, 0.f), vb = va;
      if (row < NN && k < 268) va = *(const float4*)(A32 + (size_t)row * 268 + k);
      if (row < NN && k + 4 < 268) vb = *(const float4*)(A32 + (size_t)row * 268 + k + 4);
      short8 s;
      s[0] = f2bf(va.x); s[1] = f2bf(va.y); s[2] = f2bf(va.z); s[3] = f2bf(va.w);
      s[4] = f2bf(vb.x); s[5] = f2bf(vb.y); s[6] = f2bf(vb.z); s[7] = f2bf(vb.w);
      *(short8*)(&As[sr][sko]) = s;
    }
    // stage B: 192 rows x 32 k, already bf16 (3 x 16B per thread)
#pragma unroll
    for (int i = 0; i < 3; ++i) {
      int r = sr + i * 64;
      *(short8*)(&Bs[r][sko]) = *(const short8*)(WbT + (size_t)r * KP + k0 + sko);
    }
    __syncthreads();
    short8 af[2], bf[6];
#pragma unroll
    for (int mi = 0; mi < 2; ++mi)
      af[mi] = *(const short8*)(&As[(mh * 2 + mi) * 16 + l16][quad * 8]);
#pragma unroll
    for (int ni = 0; ni < 6; ++ni)
      bf[ni] = *(const short8*)(&Bs[(nh * 6 + ni) * 16 + l16][quad * 8]);
#pragma unroll
    for (int mi = 0; mi < 2; ++mi)
#pragma unroll
      for (int ni = 0; ni < 6; ++ni)
        acc[mi][ni] = __builtin_amdgcn_mfma_f32_16x16x32_bf16(af[mi], bf[ni], acc[mi][ni], 0, 0, 0);
    __syncthreads();
  }
  // store: C/D layout col = lane&15, row = quad*4 + reg
#pragma unroll
  for (int mi = 0; mi < 2; ++mi) {
    int rbase = m0 + (mh * 2 + mi) * 16 + quad * 4;
#pragma unroll
    for (int reg = 0; reg < 4; ++reg) {
      int row = rbase + reg;
      if (row < NN) {
#pragma unroll
        for (int ni = 0; ni < 6; ++ni) {
          int col = (nh * 6 + ni) * 16 + l16;
          Yg[(size_t)row * 192 + col] = acc[mi][ni][reg];
        }
      }
    }
  }
}

// ---------------------------------------------------------------------------
// K4: batched GEMM  Y[g] = A[g] @ [W[0]|W[1]|W[2]]  (fp32, small K) — cheb2 in.
// ---------------------------------------------------------------------------
template <int KD, int NC, int SN, int TNT>
__global__ __launch_bounds__(256) void k_gemm_cat(
    const float* __restrict__ A1, const float* __restrict__ A2,
    const float* __restrict__ W, float* __restrict__ Y) {
  int g = blockIdx.y;
  int m0 = blockIdx.x * 64;
  const float* A = (g < 64) ? (A1 + (size_t)g * NN * KD) : (A2 + (size_t)(g - 64) * NN * KD);
  float* Yg = Y + (size_t)g * NN * NC;
  __shared__ float As[64][17];
  __shared__ float Bs[16][NC];
  int t = threadIdx.x;
  int tx = t & 15, ty = t >> 4;
  float acc[4][TNT];
#pragma unroll
  for (int i = 0; i < 4; ++i)
#pragma unroll
    for (int j = 0; j < TNT; ++j) acc[i][j] = 0.f;

  for (int k0 = 0; k0 < KD; k0 += 16) {
    int klim = KD - k0; if (klim > 16) klim = 16;
    {
      int kk = t & 15, rb = t >> 4;
#pragma unroll
      for (int i = 0; i < 4; ++i) {
        int r = rb + i * 16;
        int row = m0 + r;
        As[r][kk] = (row < NN && kk < klim) ? A[(size_t)row * KD + k0 + kk] : 0.f;
      }
    }
    for (int i = t; i < 16 * NC; i += 256) {
      int kk = i / NC, c = i - kk * NC;
      int kb = c / SN, j = c - kb * SN;
      Bs[kk][c] = (kk < klim) ? W[((size_t)kb * KD + (k0 + kk)) * SN + j] : 0.f;
    }
    __syncthreads();
#pragma unroll
    for (int kk = 0; kk < 16; ++kk) {
      float a[4];
#pragma unroll
      for (int i = 0; i < 4; ++i) a[i] = As[ty * 4 + i][kk];
#pragma unroll
      for (int j = 0; j < TNT; ++j) {
        float b = Bs[kk][tx * TNT + j];
#pragma unroll
        for (int i = 0; i < 4; ++i) acc[i][j] += a[i] * b;
      }
    }
    __syncthreads();
  }
#pragma unroll
  for (int i = 0; i < 4; ++i) {
    int row = m0 + ty * 4 + i;
    if (row < NN) {
#pragma unroll
      for (int j = 0; j < TNT; ++j) Yg[(size_t)row * NC + tx * TNT + j] = acc[i][j];
    }
  }
}

// ---------------------------------------------------------------------------
// CSR gather over an 8-feature chunk (one writer per output, no atomics).
// ---------------------------------------------------------------------------
__device__ __forceinline__ void gather8(float* __restrict__ dst, const float* __restrict__ src,
                                        const int2* __restrict__ cs, const int* __restrict__ rp,
                                        int t) {
  for (int item = t; item < NN * 2; item += 256) {
    int n = item >> 1, fg = item & 1;
    float4 r = make_float4(0.f, 0.f, 0.f, 0.f);
    int e1 = rp[n + 1];
    for (int e = rp[n]; e < e1; ++e) {
      int2 p = cs[e];
      float nw = __int_as_float(p.y);
      float4 sv = *(const float4*)(src + p.x * 8 + fg * 4);
      r.x += nw * sv.x; r.y += nw * sv.y; r.z += nw * sv.z; r.w += nw * sv.w;
    }
    *(float4*)(dst + n * 8 + fg * 4) = r;
  }
}

// ---------------------------------------------------------------------------
// K3: cheb1 combine. H1 = relu(Y0 - Y2 + L*(Y1 + 2*L*Y2) + b1)
// ---------------------------------------------------------------------------
__global__ __launch_bounds__(256) void k_cheb1(
    const float* __restrict__ Y, const int2* __restrict__ csr, const int* __restrict__ rowptr,
    const float* __restrict__ b1, float* __restrict__ H1) {
  int g = blockIdx.y, fb = blockIdx.x * 8;
  const float* Yg = Y + (size_t)g * NN * 192;
  const int2* cs = csr + (size_t)g * NE;
  __shared__ __align__(16) float S[NN * 8];
  __shared__ __align__(16) float T[NN * 8];
  __shared__ int rp[NN + 1];
  int t = threadIdx.x;
  for (int i = t; i < NN + 1; i += 256) rp[i] = rowptr[g * 272 + i];
  for (int i = t; i < NN * 8; i += 256) {
    int n = i >> 3, f = i & 7;
    S[i] = Yg[n * 192 + 128 + fb + f];  // Y2 chunk
  }
  __syncthreads();
  gather8(T, S, cs, rp, t);  // T = L*Y2
  __syncthreads();
  for (int i = t; i < NN * 8; i += 256) {
    int n = i >> 3, f = i & 7;
    S[i] = Yg[n * 192 + 64 + fb + f] + 2.f * T[i];  // U = Y1 + 2*L*Y2
  }
  __syncthreads();
  gather8(T, S, cs, rp, t);  // T = L*U
  __syncthreads();
  for (int i = t; i < NN * 8; i += 256) {
    int n = i >> 3, f = i & 7;
    int c = fb + f;
    float v = Yg[n * 192 + c] - Yg[n * 192 + 128 + c] + T[i] + b1[c];
    H1[((size_t)g * NN + n) * 64 + c] = fmaxf(v, 0.f);
  }
}

// ---------------------------------------------------------------------------
// K5: cheb2 combine, 8-feat chunks; output TRANSPOSED: H2T[g][f][n].
// ---------------------------------------------------------------------------
__global__ __launch_bounds__(256) void k_cheb2(
    const float* __restrict__ Yb, const int2* __restrict__ csr, const int* __restrict__ rowptr,
    const float* __restrict__ b4, float* __restrict__ H2T) {
  int g = blockIdx.y, fb = blockIdx.x * 8;
  const float* Yg = Yb + (size_t)g * NN * 96;
  const int2* cs = csr + (size_t)g * NE;
  __shared__ __align__(16) float S[NN * 8];
  __shared__ __align__(16) float T[NN * 8];
  __shared__ int rp[NN + 1];
  int t = threadIdx.x;
  for (int i = t; i < NN + 1; i += 256) rp[i] = rowptr[g * 272 + i];
  for (int i = t; i < NN * 8; i += 256) {
    int n = i >> 3, f = i & 7;
    S[i] = Yg[n * 96 + 64 + fb + f];
  }
  __syncthreads();
  gather8(T, S, cs, rp, t);
  __syncthreads();
  for (int i = t; i < NN * 8; i += 256) {
    int n = i >> 3, f = i & 7;
    S[i] = Yg[n * 96 + 32 + fb + f] + 2.f * T[i];
  }
  __syncthreads();
  gather8(T, S, cs, rp, t);
  __syncthreads();
  for (int i = t; i < NN * 8; i += 256) {
    int n = i >> 3, f = i & 7;
    int c = fb + f;
    float v = Yg[n * 96 + c] - Yg[n * 96 + 64 + c] + T[i] + b4[c];
    H2T[(size_t)g * 32 * NN + (size_t)c * NN + n] = fmaxf(v, 0.f);
  }
}

// ---------------------------------------------------------------------------
// K6/K7: plain GEMM + bias (+relu). A:[M x KD], W:[KD x NC], out:[M x NC].
// ---------------------------------------------------------------------------
template <int KD, int NC, int NCP, int TNT, bool RELU>
__global__ __launch_bounds__(256) void k_gemm_bias(
    const float* __restrict__ A, const float* __restrict__ W,
    const float* __restrict__ bias, float* __restrict__ out, int M) {
  int m0 = blockIdx.x * 64;
  __shared__ float As[64][17];
  __shared__ float Bs[16][NCP];
  int t = threadIdx.x;
  int tx = t & 15, ty = t >> 4;
  float acc[4][TNT];
#pragma unroll
  for (int i = 0; i < 4; ++i)
#pragma unroll
    for (int j = 0; j < TNT; ++j) acc[i][j] = 0.f;

  for (int k0 = 0; k0 < KD; k0 += 16) {
    int klim = KD - k0; if (klim > 16) klim = 16;
    {
      int kk = t & 15, rb = t >> 4;
#pragma unroll
      for (int i = 0; i < 4; ++i) {
        int r = rb + i * 16;
        int row = m0 + r;
        As[r][kk] = (row < M && kk < klim) ? A[(size_t)row * KD + k0 + kk] : 0.f;
      }
    }
    for (int i = t; i < 16 * NCP; i += 256) {
      int kk = i / NCP, c = i - kk * NCP;
      Bs[kk][c] = (kk < klim && c < NC) ? W[(size_t)(k0 + kk) * NC + c] : 0.f;
    }
    __syncthreads();
#pragma unroll
    for (int kk = 0; kk < 16; ++kk) {
      float a[4];
#pragma unroll
      for (int i = 0; i < 4; ++i) a[i] = As[ty * 4 + i][kk];
#pragma unroll
      for (int j = 0; j < TNT; ++j) {
        float b = Bs[kk][tx * TNT + j];
#pragma unroll
        for (int i = 0; i < 4; ++i) acc[i][j] += a[i] * b;
      }
    }
    __syncthreads();
  }
#pragma unroll
  for (int i = 0; i < 4; ++i) {
    int row = m0 + ty * 4 + i;
    if (row < M) {
#pragma unroll
      for (int j = 0; j < TNT; ++j) {
        int c = tx * TNT + j;
        if (c < NC) {
          float v = acc[i][j] + bias[c];
          if (RELU) v = fmaxf(v, 0.f);
          out[(size_t)row * NC + c] = v;
        }
      }
    }
  }
}

// ---------------------------------------------------------------------------
// K8: out[r] = Z2[r][:] . Wc3 + bc3
// ---------------------------------------------------------------------------
__global__ __launch_bounds__(256) void k_final(
    const float* __restrict__ Z2, const float* __restrict__ Wc3,
    const float* __restrict__ bc3, float* __restrict__ out) {
  __shared__ float Zs[256 * 61];
  __shared__ float w3[60];
  int b = blockIdx.x, t = threadIdx.x;
  const float* src = Z2 + (size_t)b * 256 * 60;
  for (int i = t; i < 256 * 60; i += 256) {
    int row = i / 60, col = i - row * 60;
    Zs[row * 61 + col] = src[i];
  }
  if (t < 60) w3[t] = Wc3[t];
  __syncthreads();
  float acc = bc3[0];
#pragma unroll
  for (int k = 0; k < 60; ++k) acc += Zs[t * 61 + k] * w3[k];
  out[(size_t)b * 256 + t] = acc;
}

// ---------------------------------------------------------------------------
// Workspace layout (bytes):
//   0         csr   int2[128][8192]          8,388,608
//   8388608   rp    int [128][272]             139,264
//   8527872   Y     f32 [128][268][192]     26,345,472  (reused as Y2b [..][96])
//   34873344  H1    f32 [128][268][64]       8,781,824  (H2T overlaps after H1 dead)
//   39264256  Z1    f32 [128][32][100]       1,638,400
//   40902656  Z2    f32 [128][32][60]          983,040
//   41885696  WbT   bf16[192][288]             110,592
// total ~42.0 MB
// ---------------------------------------------------------------------------
extern "C" void kernel_launch(void* const* d_in, const int* in_sizes, int n_in,
                              void* d_out, int out_size, void* d_ws, size_t ws_size,
                              hipStream_t stream) {
  (void)in_sizes; (void)n_in; (void)out_size; (void)ws_size;
  const float* x1  = (const float*)d_in[0];
  const int*   ei1 = (const int*)d_in[1];
  const float* ea1 = (const float*)d_in[2];
  const float* x2  = (const float*)d_in[3];
  const int*   ei2 = (const int*)d_in[4];
  const float* ea2 = (const float*)d_in[5];
  const float* W1  = (const float*)d_in[6];
  const float* b1  = (const float*)d_in[7];
  const float* W4  = (const float*)d_in[8];
  const float* b4  = (const float*)d_in[9];
  const float* Wc1 = (const float*)d_in[10];
  const float* bc1 = (const float*)d_in[11];
  const float* Wc2 = (const float*)d_in[12];
  const float* bc2 = (const float*)d_in[13];
  const float* Wc3 = (const float*)d_in[14];
  const float* bc3 = (const float*)d_in[15];

  char* ws = (char*)d_ws;
  int2*  csr = (int2*)(ws + 0);
  int*   rp  = (int*)(ws + 8388608);
  float* Y   = (float*)(ws + 8527872);
  float* H1  = (float*)(ws + 34873344);
  float* H2T = (float*)(ws + 34873344);
  float* Z1  = (float*)(ws + 39264256);
  float* Z2  = (float*)(ws + 40902656);
  short* WbT = (short*)(ws + 41885696);
  float* out = (float*)d_out;

  k_edge_prep<<<128, 256, 0, stream>>>(ei1, ea1, ei2, ea2, csr, rp);
  k_conv_w<<<216, 256, 0, stream>>>(W1, WbT);
  // Y = X @ [W1_0|W1_1|W1_2]  via bf16 MFMA (fp32 acc)
  k_gemm1_mfma<<<dim3(5, 128), 256, 0, stream>>>(x1, x2, WbT, Y);
  // H1 = relu(Y0 - Y2 + L*(Y1 + 2*L*Y2) + b1)
  k_cheb1<<<dim3(8, 128), 256, 0, stream>>>(Y, csr, rp, b1, H1);
  // Y2b = H1 @ [W4_0|W4_1|W4_2]  (K=64, N=96), written over the Y region
  k_gemm_cat<64, 96, 32, 6><<<dim3(5, 128), 256, 0, stream>>>(
      H1, H1 + (size_t)64 * NN * 64, W4, Y);
  // H2T = relu(cheb2) transposed -> [g][32][268]
  k_cheb2<<<dim3(4, 128), 256, 0, stream>>>(Y, csr, rp, b4, H2T);
  // classifier: stacked rows M = 128*32 = 4096 share weights
  k_gemm_bias<268, 100, 112, 7, true><<<64, 256, 0, stream>>>(H2T, Wc1, bc1, Z1, 4096);
  k_gemm_bias<100, 60, 64, 4, true><<<64, 256, 0, stream>>>(Z1, Wc2, bc2, Z2, 4096);
  k_final<<<16, 256, 0, stream>>>(Z2, Wc3, bc3, out);
}

// Round 5
// 356.071 us; speedup vs baseline: 4.1003x; 1.2961x over previous
//
#include <hip/hip_runtime.h>
#include <hip/hip_bf16.h>

#define NN 268
#define NE 8192
#define KP 288  // K=268 padded to multiple of 32

typedef short short8 __attribute__((ext_vector_type(8)));   // 8 bf16 = 4 VGPR
typedef float f32x4 __attribute__((ext_vector_type(4)));

// ---------------------------------------------------------------------------
// K1: per-graph edge prep. deg by src, dinv, nw = -dinv[src]*w*dinv[dst]
// (self-loops zeroed), CSR sorted by dst -> (src, nw) pairs + row_ptr.
// ---------------------------------------------------------------------------
__global__ __launch_bounds__(256) void k_edge_prep(
    const int* __restrict__ ei1, const float* __restrict__ ea1,
    const int* __restrict__ ei2, const float* __restrict__ ea2,
    int2* __restrict__ csr, int* __restrict__ rowptr) {
  int g = blockIdx.x;
  const int* ei = (g < 64) ? (ei1 + (size_t)g * 2 * NE) : (ei2 + (size_t)(g - 64) * 2 * NE);
  const float* ea = (g < 64) ? (ea1 + (size_t)g * NE) : (ea2 + (size_t)(g - 64) * NE);
  __shared__ float deg[NN];
  __shared__ float dinv[NN];
  __shared__ int cnt[NN];
  __shared__ int rp[NN + 1];
  int t = threadIdx.x;
  for (int n = t; n < NN; n += 256) { deg[n] = 0.f; cnt[n] = 0; }
  __syncthreads();
  for (int e = t; e < NE; e += 256) {
    int s = ei[e], d = ei[NE + e];
    float w = ea[e];
    if (s == d) w = 0.f;
    atomicAdd(&deg[s], w);
    atomicAdd(&cnt[d], 1);
  }
  __syncthreads();
  for (int n = t; n < NN; n += 256) {
    float dv = deg[n];
    dinv[n] = dv > 0.f ? rsqrtf(dv) : 0.f;
  }
  __syncthreads();
  if (t == 0) {
    int acc = 0;
    for (int n = 0; n < NN; ++n) { rp[n] = acc; acc += cnt[n]; }
    rp[NN] = acc;
  }
  __syncthreads();
  for (int n = t; n <= NN; n += 256) rowptr[g * 272 + n] = rp[n];
  for (int n = t; n < NN; n += 256) cnt[n] = rp[n];
  __syncthreads();
  for (int e = t; e < NE; e += 256) {
    int s = ei[e], d = ei[NE + e];
    float w = ea[e];
    if (s == d) w = 0.f;
    float nw = -dinv[s] * w * dinv[d];
    int pos = atomicAdd(&cnt[d], 1);
    csr[(size_t)g * NE + pos] = make_int2(s, __float_as_int(nw));
  }
}

// ---------------------------------------------------------------------------
// K1b: W1 [3][268][64] f32 -> WbT [192][288] bf16, WbT[n][k] = W1[n>>6][k][n&63]
// ---------------------------------------------------------------------------
__global__ __launch_bounds__(256) void k_conv_w(
    const float* __restrict__ W1, short* __restrict__ WbT) {
  int idx = blockIdx.x * 256 + threadIdx.x;  // 192*288 = 55296
  if (idx >= 192 * KP) return;
  int n = idx / KP, kp = idx - n * KP;
  int kb = n >> 6, j = n & 63;
  float v = (kp < 268) ? W1[((size_t)kb * 268 + kp) * 64 + j] : 0.f;
  __hip_bfloat16 h = __float2bfloat16(v);
  WbT[idx] = *reinterpret_cast<short*>(&h);
}

__device__ __forceinline__ short f2bf(float f) {
  __hip_bfloat16 h = __float2bfloat16(f);
  return *reinterpret_cast<short*>(&h);
}

// ---------------------------------------------------------------------------
// K2: big GEMM on MFMA.  Y[g] = X[g] @ [W1_0|W1_1|W1_2]  (M=268,K=268,N=192)
// X staged fp32->bf16 inline. 64x192 block, 4 waves, wave = 2x6 16x16 tiles.
// ---------------------------------------------------------------------------
__global__ __launch_bounds__(256) void k_gemm1_mfma(
    const float* __restrict__ x1, const float* __restrict__ x2,
    const short* __restrict__ WbT, float* __restrict__ Y) {
  int g = blockIdx.y;
  int m0 = blockIdx.x * 64;
  const float* A32 = (g < 64) ? (x1 + (size_t)g * NN * 268) : (x2 + (size_t)(g - 64) * NN * 268);
  float* Yg = Y + (size_t)g * NN * 192;
  __shared__ __align__(16) short As[64][40];
  __shared__ __align__(16) short Bs[192][40];
  int t = threadIdx.x;
  int w = t >> 6, lane = t & 63;
  int quad = lane >> 4, l16 = lane & 15;
  int mh = w & 1, nh = w >> 1;
  f32x4 acc[2][6];
#pragma unroll
  for (int mi = 0; mi < 2; ++mi)
#pragma unroll
    for (int ni = 0; ni < 6; ++ni) acc[mi][ni] = (f32x4){0.f, 0.f, 0.f, 0.f};

  int sr = t >> 2, sko = (t & 3) * 8;
  for (int k0 = 0; k0 < KP; k0 += 32) {
    {
      int row = m0 + sr;
      int k = k0 + sko;
      float4 va = make_float4(0.f, 0.f, 0.f, 0.f), vb = va;
      if (row < NN && k < 268) va = *(const float4*)(A32 + (size_t)row * 268 + k);
      if (row < NN && k + 4 < 268) vb = *(const float4*)(A32 + (size_t)row * 268 + k + 4);
      short8 s;
      s[0] = f2bf(va.x); s[1] = f2bf(va.y); s[2] = f2bf(va.z); s[3] = f2bf(va.w);
      s[4] = f2bf(vb.x); s[5] = f2bf(vb.y); s[6] = f2bf(vb.z); s[7] = f2bf(vb.w);
      *(short8*)(&As[sr][sko]) = s;
    }
#pragma unroll
    for (int i = 0; i < 3; ++i) {
      int r = sr + i * 64;
      *(short8*)(&Bs[r][sko]) = *(const short8*)(WbT + (size_t)r * KP + k0 + sko);
    }
    __syncthreads();
    short8 af[2], bfr[6];
#pragma unroll
    for (int mi = 0; mi < 2; ++mi)
      af[mi] = *(const short8*)(&As[(mh * 2 + mi) * 16 + l16][quad * 8]);
#pragma unroll
    for (int ni = 0; ni < 6; ++ni)
      bfr[ni] = *(const short8*)(&Bs[(nh * 6 + ni) * 16 + l16][quad * 8]);
#pragma unroll
    for (int mi = 0; mi < 2; ++mi)
#pragma unroll
      for (int ni = 0; ni < 6; ++ni)
        acc[mi][ni] = __builtin_amdgcn_mfma_f32_16x16x32_bf16(af[mi], bfr[ni], acc[mi][ni], 0, 0, 0);
    __syncthreads();
  }
#pragma unroll
  for (int mi = 0; mi < 2; ++mi) {
    int rbase = m0 + (mh * 2 + mi) * 16 + quad * 4;
#pragma unroll
    for (int reg = 0; reg < 4; ++reg) {
      int row = rbase + reg;
      if (row < NN) {
#pragma unroll
        for (int ni = 0; ni < 6; ++ni) {
          int col = (nh * 6 + ni) * 16 + l16;
          Yg[(size_t)row * 192 + col] = acc[mi][ni][reg];
        }
      }
    }
  }
}

// ---------------------------------------------------------------------------
// K4: batched GEMM  Y[g] = A[g] @ [W[0]|W[1]|W[2]]  (fp32, small K) — cheb2 in.
// ---------------------------------------------------------------------------
template <int KD, int NC, int SN, int TNT>
__global__ __launch_bounds__(256) void k_gemm_cat(
    const float* __restrict__ A1, const float* __restrict__ A2,
    const float* __restrict__ W, float* __restrict__ Y) {
  int g = blockIdx.y;
  int m0 = blockIdx.x * 64;
  const float* A = (g < 64) ? (A1 + (size_t)g * NN * KD) : (A2 + (size_t)(g - 64) * NN * KD);
  float* Yg = Y + (size_t)g * NN * NC;
  __shared__ float As[64][17];
  __shared__ float Bs[16][NC];
  int t = threadIdx.x;
  int tx = t & 15, ty = t >> 4;
  float acc[4][TNT];
#pragma unroll
  for (int i = 0; i < 4; ++i)
#pragma unroll
    for (int j = 0; j < TNT; ++j) acc[i][j] = 0.f;

  for (int k0 = 0; k0 < KD; k0 += 16) {
    int klim = KD - k0; if (klim > 16) klim = 16;
    {
      int kk = t & 15, rb = t >> 4;
#pragma unroll
      for (int i = 0; i < 4; ++i) {
        int r = rb + i * 16;
        int row = m0 + r;
        As[r][kk] = (row < NN && kk < klim) ? A[(size_t)row * KD + k0 + kk] : 0.f;
      }
    }
    for (int i = t; i < 16 * NC; i += 256) {
      int kk = i / NC, c = i - kk * NC;
      int kb = c / SN, j = c - kb * SN;
      Bs[kk][c] = (kk < klim) ? W[((size_t)kb * KD + (k0 + kk)) * SN + j] : 0.f;
    }
    __syncthreads();
#pragma unroll
    for (int kk = 0; kk < 16; ++kk) {
      float a[4];
#pragma unroll
      for (int i = 0; i < 4; ++i) a[i] = As[ty * 4 + i][kk];
#pragma unroll
      for (int j = 0; j < TNT; ++j) {
        float b = Bs[kk][tx * TNT + j];
#pragma unroll
        for (int i = 0; i < 4; ++i) acc[i][j] += a[i] * b;
      }
    }
    __syncthreads();
  }
#pragma unroll
  for (int i = 0; i < 4; ++i) {
    int row = m0 + ty * 4 + i;
    if (row < NN) {
#pragma unroll
      for (int j = 0; j < TNT; ++j) Yg[(size_t)row * NC + tx * TNT + j] = acc[i][j];
    }
  }
}

// ---------------------------------------------------------------------------
// CSR gather, node-per-thread over an 8-feature chunk:
// dst[n][0:8] = sum_e nw_e * src[src_e][0:8].  One thread owns a node's full
// edge walk for all 8 feats (halves edge-visits vs 2-lane split); unroll 4
// gives 4 independent int2+2xb128 loads in flight. No atomics.
// ---------------------------------------------------------------------------
__device__ __forceinline__ void gather8(float* __restrict__ dst, const float* __restrict__ src,
                                        const int2* __restrict__ cs, const int* __restrict__ rp,
                                        int t) {
  for (int n = t; n < NN; n += 256) {
    float4 r0 = make_float4(0.f, 0.f, 0.f, 0.f);
    float4 r1 = make_float4(0.f, 0.f, 0.f, 0.f);
    int e0 = rp[n], e1 = rp[n + 1];
#pragma unroll 4
    for (int e = e0; e < e1; ++e) {
      int2 p = cs[e];
      float nw = __int_as_float(p.y);
      float4 s0 = *(const float4*)(src + p.x * 8);
      float4 s1 = *(const float4*)(src + p.x * 8 + 4);
      r0.x += nw * s0.x; r0.y += nw * s0.y; r0.z += nw * s0.z; r0.w += nw * s0.w;
      r1.x += nw * s1.x; r1.y += nw * s1.y; r1.z += nw * s1.z; r1.w += nw * s1.w;
    }
    *(float4*)(dst + n * 8) = r0;
    *(float4*)(dst + n * 8 + 4) = r1;
  }
}

// ---------------------------------------------------------------------------
// K3: cheb1 combine. H1 = relu(Y0 - Y2 + L*(Y1 + 2*L*Y2) + b1)
// XCD swizzle: linear = bx + 8*by; all 8 chunks of a graph share linear%8
// (same XCD under round-robin dispatch) -> CSR fetched once per graph, L2-hit
// after. g = (l&7) + 8*(l>>6), chunk = (l>>3)&7.
// ---------------------------------------------------------------------------
__global__ __launch_bounds__(256) void k_cheb1(
    const float* __restrict__ Y, const int2* __restrict__ csr, const int* __restrict__ rowptr,
    const float* __restrict__ b1, float* __restrict__ H1) {
  int l = blockIdx.x + 8 * blockIdx.y;
  int g = (l & 7) + 8 * (l >> 6);
  int fb = ((l >> 3) & 7) * 8;
  const float* Yg = Y + (size_t)g * NN * 192;
  const int2* cs = csr + (size_t)g * NE;
  __shared__ __align__(16) float S[NN * 8];
  __shared__ __align__(16) float T[NN * 8];
  __shared__ int rp[NN + 1];
  int t = threadIdx.x;
  for (int i = t; i < NN + 1; i += 256) rp[i] = rowptr[g * 272 + i];
  for (int i = t; i < NN * 8; i += 256) {
    int n = i >> 3, f = i & 7;
    S[i] = Yg[n * 192 + 128 + fb + f];  // Y2 chunk
  }
  __syncthreads();
  gather8(T, S, cs, rp, t);  // T = L*Y2
  __syncthreads();
  for (int i = t; i < NN * 8; i += 256) {
    int n = i >> 3, f = i & 7;
    S[i] = Yg[n * 192 + 64 + fb + f] + 2.f * T[i];  // U = Y1 + 2*L*Y2
  }
  __syncthreads();
  gather8(T, S, cs, rp, t);  // T = L*U
  __syncthreads();
  for (int i = t; i < NN * 8; i += 256) {
    int n = i >> 3, f = i & 7;
    int c = fb + f;
    float v = Yg[n * 192 + c] - Yg[n * 192 + 128 + c] + T[i] + b1[c];
    H1[((size_t)g * NN + n) * 64 + c] = fmaxf(v, 0.f);
  }
}

// ---------------------------------------------------------------------------
// K5: cheb2 combine, 8-feat chunks; output TRANSPOSED: H2T[g][f][n].
// XCD swizzle: linear = bx + 4*by; g = (l&7) + 8*(l>>5), chunk = (l>>3)&3.
// ---------------------------------------------------------------------------
__global__ __launch_bounds__(256) void k_cheb2(
    const float* __restrict__ Yb, const int2* __restrict__ csr, const int* __restrict__ rowptr,
    const float* __restrict__ b4, float* __restrict__ H2T) {
  int l = blockIdx.x + 4 * blockIdx.y;
  int g = (l & 7) + 8 * (l >> 5);
  int fb = ((l >> 3) & 3) * 8;
  const float* Yg = Yb + (size_t)g * NN * 96;
  const int2* cs = csr + (size_t)g * NE;
  __shared__ __align__(16) float S[NN * 8];
  __shared__ __align__(16) float T[NN * 8];
  __shared__ int rp[NN + 1];
  int t = threadIdx.x;
  for (int i = t; i < NN + 1; i += 256) rp[i] = rowptr[g * 272 + i];
  for (int i = t; i < NN * 8; i += 256) {
    int n = i >> 3, f = i & 7;
    S[i] = Yg[n * 96 + 64 + fb + f];
  }
  __syncthreads();
  gather8(T, S, cs, rp, t);
  __syncthreads();
  for (int i = t; i < NN * 8; i += 256) {
    int n = i >> 3, f = i & 7;
    S[i] = Yg[n * 96 + 32 + fb + f] + 2.f * T[i];
  }
  __syncthreads();
  gather8(T, S, cs, rp, t);
  __syncthreads();
  for (int i = t; i < NN * 8; i += 256) {
    int n = i >> 3, f = i & 7;
    int c = fb + f;
    float v = Yg[n * 96 + c] - Yg[n * 96 + 64 + c] + T[i] + b4[c];
    H2T[(size_t)g * 32 * NN + (size_t)c * NN + n] = fmaxf(v, 0.f);
  }
}

// ---------------------------------------------------------------------------
// K6/K7: plain GEMM + bias (+relu). A:[M x KD], W:[KD x NC], out:[M x NC].
// ---------------------------------------------------------------------------
template <int KD, int NC, int NCP, int TNT, bool RELU>
__global__ __launch_bounds__(256) void k_gemm_bias(
    const float* __restrict__ A, const float* __restrict__ W,
    const float* __restrict__ bias, float* __restrict__ out, int M) {
  int m0 = blockIdx.x * 64;
  __shared__ float As[64][17];
  __shared__ float Bs[16][NCP];
  int t = threadIdx.x;
  int tx = t & 15, ty = t >> 4;
  float acc[4][TNT];
#pragma unroll
  for (int i = 0; i < 4; ++i)
#pragma unroll
    for (int j = 0; j < TNT; ++j) acc[i][j] = 0.f;

  for (int k0 = 0; k0 < KD; k0 += 16) {
    int klim = KD - k0; if (klim > 16) klim = 16;
    {
      int kk = t & 15, rb = t >> 4;
#pragma unroll
      for (int i = 0; i < 4; ++i) {
        int r = rb + i * 16;
        int row = m0 + r;
        As[r][kk] = (row < M && kk < klim) ? A[(size_t)row * KD + k0 + kk] : 0.f;
      }
    }
    for (int i = t; i < 16 * NCP; i += 256) {
      int kk = i / NCP, c = i - kk * NCP;
      Bs[kk][c] = (kk < klim && c < NC) ? W[(size_t)(k0 + kk) * NC + c] : 0.f;
    }
    __syncthreads();
#pragma unroll
    for (int kk = 0; kk < 16; ++kk) {
      float a[4];
#pragma unroll
      for (int i = 0; i < 4; ++i) a[i] = As[ty * 4 + i][kk];
#pragma unroll
      for (int j = 0; j < TNT; ++j) {
        float b = Bs[kk][tx * TNT + j];
#pragma unroll
        for (int i = 0; i < 4; ++i) acc[i][j] += a[i] * b;
      }
    }
    __syncthreads();
  }
#pragma unroll
  for (int i = 0; i < 4; ++i) {
    int row = m0 + ty * 4 + i;
    if (row < M) {
#pragma unroll
      for (int j = 0; j < TNT; ++j) {
        int c = tx * TNT + j;
        if (c < NC) {
          float v = acc[i][j] + bias[c];
          if (RELU) v = fmaxf(v, 0.f);
          out[(size_t)row * NC + c] = v;
        }
      }
    }
  }
}

// ---------------------------------------------------------------------------
// K8: out[r] = Z2[r][:] . Wc3 + bc3
// ---------------------------------------------------------------------------
__global__ __launch_bounds__(256) void k_final(
    const float* __restrict__ Z2, const float* __restrict__ Wc3,
    const float* __restrict__ bc3, float* __restrict__ out) {
  __shared__ float Zs[256 * 61];
  __shared__ float w3[60];
  int b = blockIdx.x, t = threadIdx.x;
  const float* src = Z2 + (size_t)b * 256 * 60;
  for (int i = t; i < 256 * 60; i += 256) {
    int row = i / 60, col = i - row * 60;
    Zs[row * 61 + col] = src[i];
  }
  if (t < 60) w3[t] = Wc3[t];
  __syncthreads();
  float acc = bc3[0];
#pragma unroll
  for (int k = 0; k < 60; ++k) acc += Zs[t * 61 + k] * w3[k];
  out[(size_t)b * 256 + t] = acc;
}

// ---------------------------------------------------------------------------
// Workspace layout (bytes):
//   0         csr   int2[128][8192]          8,388,608
//   8388608   rp    int [128][272]             139,264
//   8527872   Y     f32 [128][268][192]     26,345,472  (reused as Y2b [..][96])
//   34873344  H1    f32 [128][268][64]       8,781,824  (H2T overlaps after H1 dead)
//   39264256  Z1    f32 [128][32][100]       1,638,400
//   40902656  Z2    f32 [128][32][60]          983,040
//   41885696  WbT   bf16[192][288]             110,592
// total ~42.0 MB
// ---------------------------------------------------------------------------
extern "C" void kernel_launch(void* const* d_in, const int* in_sizes, int n_in,
                              void* d_out, int out_size, void* d_ws, size_t ws_size,
                              hipStream_t stream) {
  (void)in_sizes; (void)n_in; (void)out_size; (void)ws_size;
  const float* x1  = (const float*)d_in[0];
  const int*   ei1 = (const int*)d_in[1];
  const float* ea1 = (const float*)d_in[2];
  const float* x2  = (const float*)d_in[3];
  const int*   ei2 = (const int*)d_in[4];
  const float* ea2 = (const float*)d_in[5];
  const float* W1  = (const float*)d_in[6];
  const float* b1  = (const float*)d_in[7];
  const float* W4  = (const float*)d_in[8];
  const float* b4  = (const float*)d_in[9];
  const float* Wc1 = (const float*)d_in[10];
  const float* bc1 = (const float*)d_in[11];
  const float* Wc2 = (const float*)d_in[12];
  const float* bc2 = (const float*)d_in[13];
  const float* Wc3 = (const float*)d_in[14];
  const float* bc3 = (const float*)d_in[15];

  char* ws = (char*)d_ws;
  int2*  csr = (int2*)(ws + 0);
  int*   rp  = (int*)(ws + 8388608);
  float* Y   = (float*)(ws + 8527872);
  float* H1  = (float*)(ws + 34873344);
  float* H2T = (float*)(ws + 34873344);
  float* Z1  = (float*)(ws + 39264256);
  float* Z2  = (float*)(ws + 40902656);
  short* WbT = (short*)(ws + 41885696);
  float* out = (float*)d_out;

  k_edge_prep<<<128, 256, 0, stream>>>(ei1, ea1, ei2, ea2, csr, rp);
  k_conv_w<<<216, 256, 0, stream>>>(W1, WbT);
  // Y = X @ [W1_0|W1_1|W1_2]  via bf16 MFMA (fp32 acc)
  k_gemm1_mfma<<<dim3(5, 128), 256, 0, stream>>>(x1, x2, WbT, Y);
  // H1 = relu(Y0 - Y2 + L*(Y1 + 2*L*Y2) + b1)
  k_cheb1<<<dim3(8, 128), 256, 0, stream>>>(Y, csr, rp, b1, H1);
  // Y2b = H1 @ [W4_0|W4_1|W4_2]  (K=64, N=96), written over the Y region
  k_gemm_cat<64, 96, 32, 6><<<dim3(5, 128), 256, 0, stream>>>(
      H1, H1 + (size_t)64 * NN * 64, W4, Y);
  // H2T = relu(cheb2) transposed -> [g][32][268]
  k_cheb2<<<dim3(4, 128), 256, 0, stream>>>(Y, csr, rp, b4, H2T);
  // classifier: stacked rows M = 128*32 = 4096 share weights
  k_gemm_bias<268, 100, 112, 7, true><<<64, 256, 0, stream>>>(H2T, Wc1, bc1, Z1, 4096);
  k_gemm_bias<100, 60, 64, 4, true><<<64, 256, 0, stream>>>(Z1, Wc2, bc2, Z2, 4096);
  k_final<<<16, 256, 0, stream>>>(Z2, Wc3, bc3, out);
}

// Round 6
// 275.760 us; speedup vs baseline: 5.2944x; 1.2912x over previous
//
#include <hip/hip_runtime.h>
#include <hip/hip_bf16.h>

#define NN 268
#define NE 8192
#define KP 288  // K=268 padded to multiple of 32 (shared by gemm1 and classifier)

typedef short short8 __attribute__((ext_vector_type(8)));   // 8 bf16 = 4 VGPR
typedef float f32x4 __attribute__((ext_vector_type(4)));

// ---------------------------------------------------------------------------
// K1: per-graph edge prep. deg by src, dinv, nw = -dinv[src]*w*dinv[dst]
// (self-loops zeroed), CSR sorted by dst -> (src, nw) pairs + row_ptr.
// ---------------------------------------------------------------------------
__global__ __launch_bounds__(256) void k_edge_prep(
    const int* __restrict__ ei1, const float* __restrict__ ea1,
    const int* __restrict__ ei2, const float* __restrict__ ea2,
    int2* __restrict__ csr, int* __restrict__ rowptr) {
  int g = blockIdx.x;
  const int* ei = (g < 64) ? (ei1 + (size_t)g * 2 * NE) : (ei2 + (size_t)(g - 64) * 2 * NE);
  const float* ea = (g < 64) ? (ea1 + (size_t)g * NE) : (ea2 + (size_t)(g - 64) * NE);
  __shared__ float deg[NN];
  __shared__ float dinv[NN];
  __shared__ int cnt[NN];
  __shared__ int rp[NN + 1];
  int t = threadIdx.x;
  for (int n = t; n < NN; n += 256) { deg[n] = 0.f; cnt[n] = 0; }
  __syncthreads();
  for (int e = t; e < NE; e += 256) {
    int s = ei[e], d = ei[NE + e];
    float w = ea[e];
    if (s == d) w = 0.f;
    atomicAdd(&deg[s], w);
    atomicAdd(&cnt[d], 1);
  }
  __syncthreads();
  for (int n = t; n < NN; n += 256) {
    float dv = deg[n];
    dinv[n] = dv > 0.f ? rsqrtf(dv) : 0.f;
  }
  __syncthreads();
  if (t == 0) {
    int acc = 0;
    for (int n = 0; n < NN; ++n) { rp[n] = acc; acc += cnt[n]; }
    rp[NN] = acc;
  }
  __syncthreads();
  for (int n = t; n <= NN; n += 256) rowptr[g * 272 + n] = rp[n];
  for (int n = t; n < NN; n += 256) cnt[n] = rp[n];
  __syncthreads();
  for (int e = t; e < NE; e += 256) {
    int s = ei[e], d = ei[NE + e];
    float w = ea[e];
    if (s == d) w = 0.f;
    float nw = -dinv[s] * w * dinv[d];
    int pos = atomicAdd(&cnt[d], 1);
    csr[(size_t)g * NE + pos] = make_int2(s, __float_as_int(nw));
  }
}

__device__ __forceinline__ short f2bf(float f) {
  __hip_bfloat16 h = __float2bfloat16(f);
  return *reinterpret_cast<short*>(&h);
}

// ---------------------------------------------------------------------------
// K1b: W1 [3][268][64] f32 -> WbT [192][288] bf16, WbT[n][k] = W1[n>>6][k][n&63]
// ---------------------------------------------------------------------------
__global__ __launch_bounds__(256) void k_conv_w(
    const float* __restrict__ W1, short* __restrict__ WbT) {
  int idx = blockIdx.x * 256 + threadIdx.x;  // 192*288 = 55296
  if (idx >= 192 * KP) return;
  int n = idx / KP, kp = idx - n * KP;
  int kb = n >> 6, j = n & 63;
  float v = (kp < 268) ? W1[((size_t)kb * 268 + kp) * 64 + j] : 0.f;
  WbT[idx] = f2bf(v);
}

// ---------------------------------------------------------------------------
// K1c: Wc1 [268][100] f32 -> Wc1bT [112][288] bf16 (n-major, zero-padded).
// Launched late (after cheb1) into the dead Y-tail region.
// ---------------------------------------------------------------------------
__global__ __launch_bounds__(256) void k_conv_wc1(
    const float* __restrict__ Wc1, short* __restrict__ Wc1bT) {
  int idx = blockIdx.x * 256 + threadIdx.x;  // 112*288 = 32256
  if (idx >= 112 * KP) return;
  int n = idx / KP, k = idx - n * KP;
  float v = (n < 100 && k < 268) ? Wc1[(size_t)k * 100 + n] : 0.f;
  Wc1bT[idx] = f2bf(v);
}

// ---------------------------------------------------------------------------
// K2: big GEMM on MFMA.  Y[g] = X[g] @ [W1_0|W1_1|W1_2]  (M=268,K=268,N=192)
// X staged fp32->bf16 inline. 64x192 block, 4 waves, wave = 2x6 16x16 tiles.
// ---------------------------------------------------------------------------
__global__ __launch_bounds__(256) void k_gemm1_mfma(
    const float* __restrict__ x1, const float* __restrict__ x2,
    const short* __restrict__ WbT, float* __restrict__ Y) {
  int g = blockIdx.y;
  int m0 = blockIdx.x * 64;
  const float* A32 = (g < 64) ? (x1 + (size_t)g * NN * 268) : (x2 + (size_t)(g - 64) * NN * 268);
  float* Yg = Y + (size_t)g * NN * 192;
  __shared__ __align__(16) short As[64][40];
  __shared__ __align__(16) short Bs[192][40];
  int t = threadIdx.x;
  int w = t >> 6, lane = t & 63;
  int quad = lane >> 4, l16 = lane & 15;
  int mh = w & 1, nh = w >> 1;
  f32x4 acc[2][6];
#pragma unroll
  for (int mi = 0; mi < 2; ++mi)
#pragma unroll
    for (int ni = 0; ni < 6; ++ni) acc[mi][ni] = (f32x4){0.f, 0.f, 0.f, 0.f};

  int sr = t >> 2, sko = (t & 3) * 8;
  for (int k0 = 0; k0 < KP; k0 += 32) {
    {
      int row = m0 + sr;
      int k = k0 + sko;
      float4 va = make_float4(0.f, 0.f, 0.f, 0.f), vb = va;
      if (row < NN && k < 268) va = *(const float4*)(A32 + (size_t)row * 268 + k);
      if (row < NN && k + 4 < 268) vb = *(const float4*)(A32 + (size_t)row * 268 + k + 4);
      short8 s;
      s[0] = f2bf(va.x); s[1] = f2bf(va.y); s[2] = f2bf(va.z); s[3] = f2bf(va.w);
      s[4] = f2bf(vb.x); s[5] = f2bf(vb.y); s[6] = f2bf(vb.z); s[7] = f2bf(vb.w);
      *(short8*)(&As[sr][sko]) = s;
    }
#pragma unroll
    for (int i = 0; i < 3; ++i) {
      int r = sr + i * 64;
      *(short8*)(&Bs[r][sko]) = *(const short8*)(WbT + (size_t)r * KP + k0 + sko);
    }
    __syncthreads();
    short8 af[2], bfr[6];
#pragma unroll
    for (int mi = 0; mi < 2; ++mi)
      af[mi] = *(const short8*)(&As[(mh * 2 + mi) * 16 + l16][quad * 8]);
#pragma unroll
    for (int ni = 0; ni < 6; ++ni)
      bfr[ni] = *(const short8*)(&Bs[(nh * 6 + ni) * 16 + l16][quad * 8]);
#pragma unroll
    for (int mi = 0; mi < 2; ++mi)
#pragma unroll
      for (int ni = 0; ni < 6; ++ni)
        acc[mi][ni] = __builtin_amdgcn_mfma_f32_16x16x32_bf16(af[mi], bfr[ni], acc[mi][ni], 0, 0, 0);
    __syncthreads();
  }
#pragma unroll
  for (int mi = 0; mi < 2; ++mi) {
    int rbase = m0 + (mh * 2 + mi) * 16 + quad * 4;
#pragma unroll
    for (int reg = 0; reg < 4; ++reg) {
      int row = rbase + reg;
      if (row < NN) {
#pragma unroll
        for (int ni = 0; ni < 6; ++ni) {
          int col = (nh * 6 + ni) * 16 + l16;
          Yg[(size_t)row * 192 + col] = acc[mi][ni][reg];
        }
      }
    }
  }
}

// ---------------------------------------------------------------------------
// K4: batched GEMM  Y[g] = A[g] @ [W[0]|W[1]|W[2]]  (fp32, small K) — cheb2 in.
// ---------------------------------------------------------------------------
template <int KD, int NC, int SN, int TNT>
__global__ __launch_bounds__(256) void k_gemm_cat(
    const float* __restrict__ A1, const float* __restrict__ A2,
    const float* __restrict__ W, float* __restrict__ Y) {
  int g = blockIdx.y;
  int m0 = blockIdx.x * 64;
  const float* A = (g < 64) ? (A1 + (size_t)g * NN * KD) : (A2 + (size_t)(g - 64) * NN * KD);
  float* Yg = Y + (size_t)g * NN * NC;
  __shared__ float As[64][17];
  __shared__ float Bs[16][NC];
  int t = threadIdx.x;
  int tx = t & 15, ty = t >> 4;
  float acc[4][TNT];
#pragma unroll
  for (int i = 0; i < 4; ++i)
#pragma unroll
    for (int j = 0; j < TNT; ++j) acc[i][j] = 0.f;

  for (int k0 = 0; k0 < KD; k0 += 16) {
    int klim = KD - k0; if (klim > 16) klim = 16;
    {
      int kk = t & 15, rb = t >> 4;
#pragma unroll
      for (int i = 0; i < 4; ++i) {
        int r = rb + i * 16;
        int row = m0 + r;
        As[r][kk] = (row < NN && kk < klim) ? A[(size_t)row * KD + k0 + kk] : 0.f;
      }
    }
    for (int i = t; i < 16 * NC; i += 256) {
      int kk = i / NC, c = i - kk * NC;
      int kb = c / SN, j = c - kb * SN;
      Bs[kk][c] = (kk < klim) ? W[((size_t)kb * KD + (k0 + kk)) * SN + j] : 0.f;
    }
    __syncthreads();
#pragma unroll
    for (int kk = 0; kk < 16; ++kk) {
      float a[4];
#pragma unroll
      for (int i = 0; i < 4; ++i) a[i] = As[ty * 4 + i][kk];
#pragma unroll
      for (int j = 0; j < TNT; ++j) {
        float b = Bs[kk][tx * TNT + j];
#pragma unroll
        for (int i = 0; i < 4; ++i) acc[i][j] += a[i] * b;
      }
    }
    __syncthreads();
  }
#pragma unroll
  for (int i = 0; i < 4; ++i) {
    int row = m0 + ty * 4 + i;
    if (row < NN) {
#pragma unroll
      for (int j = 0; j < TNT; ++j) Yg[(size_t)row * NC + tx * TNT + j] = acc[i][j];
    }
  }
}

// ---------------------------------------------------------------------------
// CSR gather, node-per-thread over an 8-feature chunk (no atomics).
// ---------------------------------------------------------------------------
__device__ __forceinline__ void gather8(float* __restrict__ dst, const float* __restrict__ src,
                                        const int2* __restrict__ cs, const int* __restrict__ rp,
                                        int t) {
  for (int n = t; n < NN; n += 256) {
    float4 r0 = make_float4(0.f, 0.f, 0.f, 0.f);
    float4 r1 = make_float4(0.f, 0.f, 0.f, 0.f);
    int e0 = rp[n], e1 = rp[n + 1];
#pragma unroll 4
    for (int e = e0; e < e1; ++e) {
      int2 p = cs[e];
      float nw = __int_as_float(p.y);
      float4 s0 = *(const float4*)(src + p.x * 8);
      float4 s1 = *(const float4*)(src + p.x * 8 + 4);
      r0.x += nw * s0.x; r0.y += nw * s0.y; r0.z += nw * s0.z; r0.w += nw * s0.w;
      r1.x += nw * s1.x; r1.y += nw * s1.y; r1.z += nw * s1.z; r1.w += nw * s1.w;
    }
    *(float4*)(dst + n * 8) = r0;
    *(float4*)(dst + n * 8 + 4) = r1;
  }
}

// ---------------------------------------------------------------------------
// K3: cheb1 combine. H1 = relu(Y0 - Y2 + L*(Y1 + 2*L*Y2) + b1)
// XCD swizzle: all 8 chunks of a graph share linear%8 -> same XCD L2.
// ---------------------------------------------------------------------------
__global__ __launch_bounds__(256) void k_cheb1(
    const float* __restrict__ Y, const int2* __restrict__ csr, const int* __restrict__ rowptr,
    const float* __restrict__ b1, float* __restrict__ H1) {
  int l = blockIdx.x + 8 * blockIdx.y;
  int g = (l & 7) + 8 * (l >> 6);
  int fb = ((l >> 3) & 7) * 8;
  const float* Yg = Y + (size_t)g * NN * 192;
  const int2* cs = csr + (size_t)g * NE;
  __shared__ __align__(16) float S[NN * 8];
  __shared__ __align__(16) float T[NN * 8];
  __shared__ int rp[NN + 1];
  int t = threadIdx.x;
  for (int i = t; i < NN + 1; i += 256) rp[i] = rowptr[g * 272 + i];
  for (int i = t; i < NN * 8; i += 256) {
    int n = i >> 3, f = i & 7;
    S[i] = Yg[n * 192 + 128 + fb + f];  // Y2 chunk
  }
  __syncthreads();
  gather8(T, S, cs, rp, t);  // T = L*Y2
  __syncthreads();
  for (int i = t; i < NN * 8; i += 256) {
    int n = i >> 3, f = i & 7;
    S[i] = Yg[n * 192 + 64 + fb + f] + 2.f * T[i];  // U = Y1 + 2*L*Y2
  }
  __syncthreads();
  gather8(T, S, cs, rp, t);  // T = L*U
  __syncthreads();
  for (int i = t; i < NN * 8; i += 256) {
    int n = i >> 3, f = i & 7;
    int c = fb + f;
    float v = Yg[n * 192 + c] - Yg[n * 192 + 128 + c] + T[i] + b1[c];
    H1[((size_t)g * NN + n) * 64 + c] = fmaxf(v, 0.f);
  }
}

// ---------------------------------------------------------------------------
// K5: cheb2 combine, 8-feat chunks; output = classifier A-matrix:
// H2Tb bf16 [4096 rows=(g,f)][KP=288], k (=node) zero-padded 268..287.
// ---------------------------------------------------------------------------
__global__ __launch_bounds__(256) void k_cheb2(
    const float* __restrict__ Yb, const int2* __restrict__ csr, const int* __restrict__ rowptr,
    const float* __restrict__ b4, short* __restrict__ H2Tb) {
  int l = blockIdx.x + 4 * blockIdx.y;
  int g = (l & 7) + 8 * (l >> 5);
  int fb = ((l >> 3) & 3) * 8;
  const float* Yg = Yb + (size_t)g * NN * 96;
  const int2* cs = csr + (size_t)g * NE;
  __shared__ __align__(16) float S[NN * 8];
  __shared__ __align__(16) float T[NN * 8];
  __shared__ int rp[NN + 1];
  int t = threadIdx.x;
  for (int i = t; i < NN + 1; i += 256) rp[i] = rowptr[g * 272 + i];
  for (int i = t; i < NN * 8; i += 256) {
    int n = i >> 3, f = i & 7;
    S[i] = Yg[n * 96 + 64 + fb + f];
  }
  __syncthreads();
  gather8(T, S, cs, rp, t);
  __syncthreads();
  for (int i = t; i < NN * 8; i += 256) {
    int n = i >> 3, f = i & 7;
    S[i] = Yg[n * 96 + 32 + fb + f] + 2.f * T[i];
  }
  __syncthreads();
  gather8(T, S, cs, rp, t);
  __syncthreads();
  // write bf16, f slow / n fast for coalesced short stores
  for (int i = t; i < NN * 8; i += 256) {
    int f = i / NN, n = i - f * NN;
    int c = fb + f;
    float v = Yg[n * 96 + c] - Yg[n * 96 + 64 + c] + T[n * 8 + f] + b4[c];
    H2Tb[((size_t)g * 32 + c) * KP + n] = f2bf(fmaxf(v, 0.f));
  }
  // zero the k-pad 268..287 for this block's 8 rows
  for (int i = t; i < 8 * (KP - NN); i += 256) {
    int f = i / (KP - NN), n = NN + (i - f * (KP - NN));
    H2Tb[((size_t)g * 32 + fb + f) * KP + n] = 0;
  }
}

// ---------------------------------------------------------------------------
// K6: fused classifier. Per block: 64 rows of H2Tb [4096][288] bf16.
// L1: MFMA 64x112 (K=288) -> Z1=relu(.+bc1) in LDS (fp32).
// L2: Z2=relu(Z1@Wc2+bc2) register-tiled 2x8 from LDS (fp32).
// L3: out = Z2 . Wc3 + bc3.  Rows (g*32+c) match d_out order.
// ---------------------------------------------------------------------------
__global__ __launch_bounds__(256) void k_cls(
    const short* __restrict__ H2Tb, const short* __restrict__ Wc1bT,
    const float* __restrict__ bc1, const float* __restrict__ Wc2,
    const float* __restrict__ bc2, const float* __restrict__ Wc3,
    const float* __restrict__ bc3, float* __restrict__ out) {
  int m0 = blockIdx.x * 64;
  __shared__ __align__(16) short As[64][40];
  __shared__ __align__(16) short Bs[112][40];
  __shared__ __align__(16) float Z1s[64][116];
  __shared__ __align__(16) float W2s[100][64];
  __shared__ __align__(16) float Z2s[64][64];
  __shared__ float w3s[64];
  int t = threadIdx.x;
  int w = t >> 6, lane = t & 63;
  int quad = lane >> 4, l16 = lane & 15;
  f32x4 acc[7];
#pragma unroll
  for (int ni = 0; ni < 7; ++ni) acc[ni] = (f32x4){0.f, 0.f, 0.f, 0.f};

  int sr = t >> 2, sko = (t & 3) * 8;
  for (int k0 = 0; k0 < KP; k0 += 32) {
    *(short8*)(&As[sr][sko]) = *(const short8*)(H2Tb + (size_t)(m0 + sr) * KP + k0 + sko);
#pragma unroll
    for (int i = 0; i < 2; ++i) {
      int idx = t + i * 256;
      if (idx < 112 * 4) {
        int r = idx >> 2, ko = (idx & 3) * 8;
        *(short8*)(&Bs[r][ko]) = *(const short8*)(Wc1bT + (size_t)r * KP + k0 + ko);
      }
    }
    __syncthreads();
    short8 af = *(const short8*)(&As[w * 16 + l16][quad * 8]);
#pragma unroll
    for (int ni = 0; ni < 7; ++ni) {
      short8 bfr = *(const short8*)(&Bs[ni * 16 + l16][quad * 8]);
      acc[ni] = __builtin_amdgcn_mfma_f32_16x16x32_bf16(af, bfr, acc[ni], 0, 0, 0);
    }
    __syncthreads();
  }
  // L1 epilogue: Z1s = relu(acc + bc1); C/D: col=lane&15, row=quad*4+reg
#pragma unroll
  for (int ni = 0; ni < 7; ++ni) {
    int col = ni * 16 + l16;
    if (col < 100) {
      float b = bc1[col];
#pragma unroll
      for (int reg = 0; reg < 4; ++reg) {
        int wrow = w * 16 + quad * 4 + reg;
        Z1s[wrow][col] = fmaxf(acc[ni][reg] + b, 0.f);
      }
    }
  }
  // stage Wc2 (zero-pad cols 60..63) and Wc3
  for (int i = t; i < 100 * 64; i += 256) {
    int r = i >> 6, c = i & 63;
    W2s[r][c] = (c < 60) ? Wc2[(size_t)r * 60 + c] : 0.f;
  }
  if (t < 64) w3s[t] = (t < 60) ? Wc3[t] : 0.f;
  __syncthreads();
  // L2: rows 2 x cols 8 per thread
  {
    int r2 = (t >> 3) * 2;
    int c8 = (t & 7) * 8;
    float a2[2][8];
#pragma unroll
    for (int i = 0; i < 2; ++i)
#pragma unroll
      for (int j = 0; j < 8; ++j) a2[i][j] = 0.f;
#pragma unroll 4
    for (int k = 0; k < 100; ++k) {
      float x0 = Z1s[r2][k], x1 = Z1s[r2 + 1][k];
      float4 wA = *(const float4*)(&W2s[k][c8]);
      float4 wB = *(const float4*)(&W2s[k][c8 + 4]);
      float wv[8] = {wA.x, wA.y, wA.z, wA.w, wB.x, wB.y, wB.z, wB.w};
#pragma unroll
      for (int j = 0; j < 8; ++j) { a2[0][j] += x0 * wv[j]; a2[1][j] += x1 * wv[j]; }
    }
#pragma unroll
    for (int j = 0; j < 8; ++j) {
      int c = c8 + j;
      float bb = (c < 60) ? bc2[c] : 0.f;
      Z2s[r2][c] = fmaxf(a2[0][j] + bb, 0.f);
      Z2s[r2 + 1][c] = fmaxf(a2[1][j] + bb, 0.f);
    }
  }
  __syncthreads();
  // L3
  if (t < 64) {
    float acc3 = bc3[0];
#pragma unroll
    for (int k = 0; k < 60; ++k) acc3 += Z2s[t][k] * w3s[k];
    out[m0 + t] = acc3;
  }
}

// ---------------------------------------------------------------------------
// Workspace layout (bytes):
//   0         csr    int2[128][8192]          8,388,608
//   8388608   rp     int [128][272]             139,264
//   8527872   Y      f32 [128][268][192]     26,345,472
//               Y2b (gemm_cat out) occupies Y[0 .. 13,172,736)
//   21700608  Wc1bT  bf16[112][288]              64,512   (written after Y tail dead)
//   34873344  H1     f32 [128][268][64]       8,781,824
//   34873344  H2Tb   bf16[4096][288]          2,359,296   (over dead H1 head)
//   41885696  WbT    bf16[192][288]             110,592   (inside H1 tail; consumed
//                                                          by gemm1 before cheb1 writes H1)
// high-water 43,655,168 (H1 end) — same as previous rounds.
// ---------------------------------------------------------------------------
extern "C" void kernel_launch(void* const* d_in, const int* in_sizes, int n_in,
                              void* d_out, int out_size, void* d_ws, size_t ws_size,
                              hipStream_t stream) {
  (void)in_sizes; (void)n_in; (void)out_size; (void)ws_size;
  const float* x1  = (const float*)d_in[0];
  const int*   ei1 = (const int*)d_in[1];
  const float* ea1 = (const float*)d_in[2];
  const float* x2  = (const float*)d_in[3];
  const int*   ei2 = (const int*)d_in[4];
  const float* ea2 = (const float*)d_in[5];
  const float* W1  = (const float*)d_in[6];
  const float* b1  = (const float*)d_in[7];
  const float* W4  = (const float*)d_in[8];
  const float* b4  = (const float*)d_in[9];
  const float* Wc1 = (const float*)d_in[10];
  const float* bc1 = (const float*)d_in[11];
  const float* Wc2 = (const float*)d_in[12];
  const float* bc2 = (const float*)d_in[13];
  const float* Wc3 = (const float*)d_in[14];
  const float* bc3 = (const float*)d_in[15];

  char* ws = (char*)d_ws;
  int2*  csr   = (int2*)(ws + 0);
  int*   rp    = (int*)(ws + 8388608);
  float* Y     = (float*)(ws + 8527872);
  short* Wc1bT = (short*)(ws + 21700608);
  float* H1    = (float*)(ws + 34873344);
  short* H2Tb  = (short*)(ws + 34873344);
  short* WbT   = (short*)(ws + 41885696);
  float* out   = (float*)d_out;

  k_edge_prep<<<128, 256, 0, stream>>>(ei1, ea1, ei2, ea2, csr, rp);
  k_conv_w<<<216, 256, 0, stream>>>(W1, WbT);
  // Y = X @ [W1_0|W1_1|W1_2]  via bf16 MFMA (fp32 acc); consumes WbT
  k_gemm1_mfma<<<dim3(5, 128), 256, 0, stream>>>(x1, x2, WbT, Y);
  // H1 = relu(Y0 - Y2 + L*(Y1 + 2*L*Y2) + b1)   (overwrites WbT region — dead)
  k_cheb1<<<dim3(8, 128), 256, 0, stream>>>(Y, csr, rp, b1, H1);
  // Y2b = H1 @ [W4_0|W4_1|W4_2]  (K=64, N=96) over Y head
  k_gemm_cat<64, 96, 32, 6><<<dim3(5, 128), 256, 0, stream>>>(
      H1, H1 + (size_t)64 * NN * 64, W4, Y);
  // Wc1 -> bf16 into dead Y tail
  k_conv_wc1<<<126, 256, 0, stream>>>(Wc1, Wc1bT);
  // H2Tb = relu(cheb2) as bf16 classifier A-matrix (over dead H1 head)
  k_cheb2<<<dim3(4, 128), 256, 0, stream>>>(Y, csr, rp, b4, H2Tb);
  // fused classifier: MFMA L1 + fp32 L2/L3
  k_cls<<<64, 256, 0, stream>>>(H2Tb, Wc1bT, bc1, Wc2, bc2, Wc3, bc3, out);
}